// Round 1
// baseline (133.297 us; speedup 1.0000x reference)
//
#include <hip/hip_runtime.h>

// RoPEAttention MI355X round 14:
//  qkv : NEW 256x256 BK=64 4-phase counted-vmcnt schedule (m201/m248 template).
//        2-phase 128^2 was at its structural ceiling (618 TF ~= m233's 607).
//        Stage units SA0/SB0/SB1/SA1 one-per-phase into the other dbuf;
//        vmcnt(4) at 3/4 phase starts (never 0 in steady loop); 1 barrier/phase.
//  attn/proj/prep/vtrans: unchanged from round 13 (118.2 us).

typedef __bf16 bf16;
typedef __bf16 bf16x4 __attribute__((ext_vector_type(4)));
typedef __bf16 bf16x8 __attribute__((ext_vector_type(8)));
typedef float f32x4 __attribute__((ext_vector_type(4)));

namespace {
constexpr int kC = 768;
constexpr int kNtok = 577;
constexpr int kM = 16 * kNtok;     // 9232
constexpr int kMpad = 9472;        // 37 * 256
constexpr int kTok = 640;
constexpr int kBH = 192;
}

typedef __attribute__((address_space(3))) unsigned int as3_u32;
typedef __attribute__((address_space(1))) unsigned int as1_u32;
__device__ __forceinline__ void gl16(const bf16* g, bf16* l) {
  __builtin_amdgcn_global_load_lds((const as1_u32*)g, (as3_u32*)l, 16, 0, 0);
}

// m204 bijective XCD swizzle
__device__ __forceinline__ int swz_lid(int hid, int nwg) {
  int q = nwg >> 3, r = nwg & 7;
  int x = hid & 7, y = hid >> 3;
  int base = (x < r) ? x * (q + 1) : r * (q + 1) + (x - r) * q;
  return base + y;
}

// ---------------- fused prep: conv_x | conv_w(qkv) | conv_w(proj) | rope --------
__global__ __launch_bounds__(256) void prep_kernel(
    const float* __restrict__ x, const float* __restrict__ qkv_w,
    const float* __restrict__ proj_w, const float* __restrict__ freqs,
    bf16* __restrict__ xb, bf16* __restrict__ wqb, bf16* __restrict__ pwb,
    float* __restrict__ cosT, float* __restrict__ sinT) {
  const int bidx = (int)blockIdx.x;
  const int tid = (int)threadIdx.x;
  if (bidx < 3552) {                       // conv_x: kMpad*96 chunks of 8
    int idx = bidx * 256 + tid;
    int m = idx / 96, c8 = (idx % 96) * 8;
    bf16x8 o;
    if (m < kM) {
      const float* p = x + (size_t)m * kC + c8;
#pragma unroll
      for (int j = 0; j < 8; ++j) o[j] = (bf16)p[j];
    } else {
#pragma unroll
      for (int j = 0; j < 8; ++j) o[j] = (bf16)0.0f;
    }
    *(bf16x8*)(xb + (size_t)m * kC + c8) = o;
  } else if (bidx < 3552 + 864) {          // conv_w qkv: 2304*768
    int off = ((bidx - 3552) * 256 + tid) * 8;
    bf16x8 o;
#pragma unroll
    for (int j = 0; j < 8; ++j) o[j] = (bf16)qkv_w[off + j];
    *(bf16x8*)(wqb + off) = o;
  } else if (bidx < 3552 + 864 + 288) {    // conv_w proj: 768*768
    int off = ((bidx - 3552 - 864) * 256 + tid) * 8;
    bf16x8 o;
#pragma unroll
    for (int j = 0; j < 8; ++j) o[j] = (bf16)proj_w[off + j];
    *(bf16x8*)(pwb + off) = o;
  } else {                                 // rope table: 12*576*32
    int idx = (bidx - 3552 - 864 - 288) * 256 + tid;
    int f = idx & 31;
    int t = (idx >> 5) % 576;
    int h = idx / (576 * 32);
    float ang = (float)(t % 24) * freqs[h * 32 + f] + (float)(t / 24) * freqs[384 + h * 32 + f];
    float s, c;
    sincosf(ang, &s, &c);
    cosT[idx] = c;
    sinT[idx] = s;
  }
}

// ---------------- qkv GEMM 256x256, 8 waves, BK=64, 4-phase counted vmcnt -------
// Waves 2(M)x4(N), per-wave 128x64 out. LDS 128KB dynamic: buf b at smem+b*64KB,
// A[256][64] then B[256][64]. Stage units (16KB = 2 gl16/thread):
//   SA0 = A rows {0-63,128-191}, SA1 = {64-127,192-255}  (quadrant h rows)
//   SB0 = B rows with (row&63)<32, SB1 = rest            (quadrant b rows)
// Phase p of tile t stages unit p of tile t+1 (order SA0,SB0,SB1,SA1) into the
// other buffer; vmcnt(4) at start of phases 0,1,2 retires exactly the units the
// phase consumes (verified in-flight ledger: 8 loads at boundary, lead >= 3 ph).
__global__ __launch_bounds__(512, 2) void qkv_gemm_kernel(
    const bf16* __restrict__ xb, const bf16* __restrict__ wb,
    const float* __restrict__ cosT, const float* __restrict__ sinT,
    bf16* __restrict__ qh, bf16* __restrict__ kbq, bf16* __restrict__ vb) {
  extern __shared__ __align__(16) char smem[];
  const int tid = (int)threadIdx.x;
  const int l = tid & 63, w = tid >> 6;
  const int lr = l & 15, lg = l >> 4;
  const int wm = w >> 2, wn = w & 3;
  const int w8 = w * 8;

  const int lid = swz_lid((int)blockIdx.x, 37 * 9);
  const int n0 = (lid % 9) * 256, m0 = (lid / 9) * 256;

  const int gch = (l & 7) ^ ((l >> 3) & 7);    // pre-swizzled global chunk
  const bf16* aG = xb + (size_t)(m0 + w8 + (l >> 3)) * kC + gch * 8;
  const bf16* bG = wb + (size_t)(n0 + w8 + (l >> 3)) * kC + gch * 8;

  auto Abuf = [&](int b) { return (bf16*)(smem + b * 65536); };
  auto Bbuf = [&](int b) { return (bf16*)(smem + b * 65536 + 32768); };

  auto SA = [&](int b, int k0, int half) {     // 2 loads: rows half*64, half*64+128
    bf16* A = Abuf(b);
    gl16(aG + (size_t)(half * 64) * kC + k0, A + (half * 64 + w8) * 64);
    gl16(aG + (size_t)(half * 64 + 128) * kC + k0, A + (half * 64 + 128 + w8) * 64);
  };
  auto SB = [&](int b, int k0, int bh) {       // rows with (row&63) in bh half
    bf16* B = Bbuf(b);
    const int base = w8 + (w8 & 32) + bh * 32;
    gl16(bG + (size_t)(base - w8) * kC + k0, B + base * 64);
    gl16(bG + (size_t)(base - w8 + 128) * kC + k0, B + (base + 128) * 64);
  };

  f32x4 acc[8][4];
  const f32x4 z = {0.f, 0.f, 0.f, 0.f};
#pragma unroll
  for (int mi = 0; mi < 8; ++mi)
#pragma unroll
    for (int ni = 0; ni < 4; ++ni) acc[mi][ni] = z;

  bf16x8 af[4][2], b0f[2][2], b1f[2][2];

  auto RDA = [&](int b, int H) {
    const bf16* A = Abuf(b);
#pragma unroll
    for (int mi = 0; mi < 4; ++mi) {
      const int row = wm * 128 + (H * 4 + mi) * 16 + lr;
#pragma unroll
      for (int kc = 0; kc < 2; ++kc)
        af[mi][kc] = *(const bf16x8*)&A[row * 64 + (((kc * 4 + lg) ^ (lr & 7)) << 3)];
    }
  };
  auto RDB = [&](int b, int Bs, bf16x8 (*dst)[2]) {
    const bf16* Bp = Bbuf(b);
#pragma unroll
    for (int nj = 0; nj < 2; ++nj) {
      const int row = wn * 64 + (Bs * 2 + nj) * 16 + lr;
#pragma unroll
      for (int kc = 0; kc < 2; ++kc)
        dst[nj][kc] = *(const bf16x8*)&Bp[row * 64 + (((kc * 4 + lg) ^ (lr & 7)) << 3)];
    }
  };
  auto MM = [&](int H, int Bs, bf16x8 (*bq)[2]) {
    __builtin_amdgcn_s_setprio(1);
#pragma unroll
    for (int kc = 0; kc < 2; ++kc)
#pragma unroll
      for (int mi = 0; mi < 4; ++mi)
#pragma unroll
        for (int nj = 0; nj < 2; ++nj)
          acc[H * 4 + mi][Bs * 2 + nj] = __builtin_amdgcn_mfma_f32_16x16x32_bf16(
              af[mi][kc], bq[nj][kc], acc[H * 4 + mi][Bs * 2 + nj], 0, 0, 0);
    __builtin_amdgcn_s_setprio(0);
  };
  auto BAR = [&](int n) {
    if (n == 0) asm volatile("s_waitcnt vmcnt(0)" ::: "memory");
    else if (n == 2) asm volatile("s_waitcnt vmcnt(2)" ::: "memory");
    else if (n == 4) asm volatile("s_waitcnt vmcnt(4)" ::: "memory");
    __builtin_amdgcn_sched_barrier(0);
    __builtin_amdgcn_s_barrier();
    __builtin_amdgcn_sched_barrier(0);
  };

  // prologue: stage all of tile 0 into buf0 (8 loads in flight = boundary invariant)
  SA(0, 0, 0);
  SB(0, 0, 0);
  SB(0, 0, 1);
  SA(0, 0, 1);

#pragma unroll 1
  for (int t = 0; t < 11; ++t) {
    const int cb = t & 1, nb = cb ^ 1;
    const int k1 = (t + 1) * 64;
    BAR(4);  RDA(cb, 0); RDB(cb, 0, b0f); SA(nb, k1, 0); MM(0, 0, b0f);
    BAR(4);  RDB(cb, 1, b1f);             SB(nb, k1, 0); MM(0, 1, b1f);
    BAR(4);  RDA(cb, 1);                  SB(nb, k1, 1); MM(1, 1, b1f);
    BAR(-1); RDB(cb, 0, b0f);             SA(nb, k1, 1); MM(1, 0, b0f);
  }
  {  // tile 11: no staging; epilogue drain 4 -> 2 -> 0
    const int cb = 1;
    BAR(4);  RDA(cb, 0); RDB(cb, 0, b0f); MM(0, 0, b0f);
    BAR(2);  RDB(cb, 1, b1f);             MM(0, 1, b1f);
    BAR(0);  RDA(cb, 1);                  MM(1, 1, b1f);
    BAR(-1); RDB(cb, 0, b0f);             MM(1, 0, b0f);
  }

  // ---- epilogue: restage fp32 acc in LDS (16KB/wave, 2 chunks of 64 rows),
  //      vectorized RoPE + coalesced stores ----
  __builtin_amdgcn_sched_barrier(0);
  __syncthreads();
  float* tp = (float*)smem + w * 4096;     // wave-private 64x64 f32 (16 KB)
  const int nbase = n0 + wn * 64;
  const int which = nbase / kC;
  const int h = (nbase % kC) >> 6;         // wave-uniform head
  bf16* dst = (which == 0) ? qh : (which == 1) ? kbq : vb;
  const float sc = (which == 0) ? 0.125f : 1.0f;
  const int c4 = lr * 4;
#pragma unroll
  for (int ch = 0; ch < 2; ++ch) {
#pragma unroll
    for (int mi = 0; mi < 4; ++mi)
#pragma unroll
      for (int ni = 0; ni < 4; ++ni)
#pragma unroll
        for (int r = 0; r < 4; ++r)
          tp[(mi * 16 + lg * 4 + r) * 64 + ni * 16 + lr] = acc[ch * 4 + mi][ni][r];
#pragma unroll
    for (int i = 0; i < 16; ++i) {
      const int row = i * 4 + lg;
      const int m = m0 + wm * 128 + ch * 64 + row;
      if (m >= kM) continue;
      float4 v4 = *(const float4*)&tp[row * 64 + c4];
      const int b = m / kNtok;
      const int tok = m - b * kNtok;
      float e0 = v4.x, o0 = v4.y, e1 = v4.z, o1 = v4.w;
      if (which < 2 && tok > 0) {
        const int tb = (h * 576 + tok - 1) * 32 + (c4 >> 1);
        float2 cc = *(const float2*)&cosT[tb];
        float2 ss = *(const float2*)&sinT[tb];
        float r0 = e0 * cc.x - o0 * ss.x, i0 = e0 * ss.x + o0 * cc.x;
        float r1 = e1 * cc.y - o1 * ss.y, i1 = e1 * ss.y + o1 * cc.y;
        e0 = r0; o0 = i0; e1 = r1; o1 = i1;
      }
      bf16x4 ov;
      ov[0] = (bf16)(e0 * sc); ov[1] = (bf16)(o0 * sc);
      ov[2] = (bf16)(e1 * sc); ov[3] = (bf16)(o1 * sc);
      *(bf16x4*)(dst + (((size_t)(b * 12 + h)) * kTok + tok) * 64 + c4) = ov;
    }
  }
}

// ---------------- V transpose ----------------
__global__ __launch_bounds__(256) void vtrans_kernel(const bf16* __restrict__ vb,
                                                     bf16* __restrict__ vtb) {
  __shared__ __align__(16) bf16 T[64][72];
  const int bh = (int)blockIdx.x, s = (int)blockIdx.y;
  const int t = (int)threadIdx.x;
  const int row = t >> 2, qr = t & 3;
  const int tok = s * 64 + row;
  bf16x8 v0, v1;
  if (tok < kNtok) {
    const bf16* p = vb + ((size_t)bh * kTok + tok) * 64 + qr * 16;
    v0 = *(const bf16x8*)p;
    v1 = *(const bf16x8*)(p + 8);
  } else {
#pragma unroll
    for (int j = 0; j < 8; ++j) { v0[j] = (bf16)0.0f; v1[j] = (bf16)0.0f; }
  }
#pragma unroll
  for (int j = 0; j < 8; ++j) {
    T[qr * 16 + j][row] = v0[j];
    T[qr * 16 + 8 + j][row] = v1[j];
  }
  __syncthreads();
  const int d = row;
  bf16x8 o0 = *(const bf16x8*)&T[d][qr * 16];
  bf16x8 o1 = *(const bf16x8*)&T[d][qr * 16 + 8];
  bf16* dst = vtb + ((size_t)bh * 64 + d) * kTok + s * 64 + qr * 16;
  *(bf16x8*)dst = o0;
  *(bf16x8*)(dst + 8) = o1;
}

// ---------------- flash attention: 9 exact K-tiles + key-576 correction ---------
__global__ __launch_bounds__(512, 8) void attn_kernel(
    const bf16* __restrict__ qh, const bf16* __restrict__ kbq, const bf16* __restrict__ vtb,
    bf16* __restrict__ aoh) {
  __shared__ __align__(16) bf16 Ks[2][64 * 64];   // 16 KB
  __shared__ __align__(16) bf16 Vs[2][64 * 64];   // 16 KB
  __shared__ __align__(16) bf16 Ps[8][16 * 64];   // 16 KB
  const int tid = (int)threadIdx.x;
  const int l = tid & 63, w = tid >> 6;           // 8 waves
  const int lr = l & 15, lg = l >> 4;

  const int lid = swz_lid((int)blockIdx.x, 5 * kBH);
  const int bh = lid / 5, qt = lid - bh * 5;      // all 5 q-tiles of a bh -> one XCD
  const int q0 = qt * 128;

  const int srow = w * 8 + (l >> 3);
  const int gch = (l & 7) ^ ((l >> 3) & 7);
  const bf16* kG = kbq + ((size_t)bh * kTok + srow) * 64 + gch * 8;
  const bf16* vG = vtb + ((size_t)bh * 64 + srow) * kTok + gch * 8;

  auto STAGE = [&](int buf, int j0) {
    gl16(kG + (size_t)j0 * 64, &Ks[buf][(w * 8) * 64]);
    gl16(vG + j0, &Vs[buf][(w * 8) * 64]);
  };

  bf16x8 qf[2];
  {
    const bf16* qp = qh + ((size_t)bh * kTok + (q0 + w * 16 + lr)) * 64 + lg * 8;
    qf[0] = *(const bf16x8*)qp;
    qf[1] = *(const bf16x8*)(qp + 32);
  }
  bf16x8 ones;
#pragma unroll
  for (int j = 0; j < 8; ++j) ones[j] = (bf16)1.0f;

  const f32x4 z = {0.f, 0.f, 0.f, 0.f};
  f32x4 o[4];
#pragma unroll
  for (int nf = 0; nf < 4; ++nf) o[nf] = z;
  f32x4 den = z;

  STAGE(0, 0);
#pragma unroll 1
  for (int jt = 0; jt < 9; ++jt) {              // 9 tiles = keys 0..575 exactly
    const int cur = jt & 1;
    __syncthreads();               // drains vmcnt(0): tile jt DMA done; prev reads done
    if (jt < 8) STAGE(cur ^ 1, (jt + 1) * 64);  // DMA overlaps compute below

    // S = Q K^T
    f32x4 s[4];
#pragma unroll
    for (int ni = 0; ni < 4; ++ni) s[ni] = z;
    __builtin_amdgcn_s_setprio(1);
#pragma unroll
    for (int kc = 0; kc < 2; ++kc) {
#pragma unroll
      for (int ni = 0; ni < 4; ++ni) {
        int row = ni * 16 + lr;
        bf16x8 kf = *(const bf16x8*)&Ks[cur][row * 64 + (((kc * 4 + lg) ^ (row & 7)) << 3)];
        s[ni] = __builtin_amdgcn_mfma_f32_16x16x32_bf16(qf[kc], kf, s[ni], 0, 0, 0);
      }
    }
    __builtin_amdgcn_s_setprio(0);

    // P = exp(S)  (no masking needed: all 64 keys of every tile are valid)
#pragma unroll
    for (int ni = 0; ni < 4; ++ni)
#pragma unroll
      for (int r = 0; r < 4; ++r) {
        float p = __expf(s[ni][r]);
        int prow = lg * 4 + r;
        int pcol = ni * 16 + lr;
        Ps[w][prow * 64 + ((((pcol >> 3) ^ (prow & 7)) & 7) << 3) + (pcol & 7)] = (bf16)p;
      }

    // O += P V ; den += P 1
    __builtin_amdgcn_s_setprio(1);
#pragma unroll
    for (int kc = 0; kc < 2; ++kc) {
      bf16x8 pf = *(const bf16x8*)&Ps[w][lr * 64 + (((kc * 4 + lg) ^ (lr & 7)) << 3)];
      den = __builtin_amdgcn_mfma_f32_16x16x32_bf16(pf, ones, den, 0, 0, 0);
#pragma unroll
      for (int nf = 0; nf < 4; ++nf) {
        int row = nf * 16 + lr;
        bf16x8 vf = *(const bf16x8*)&Vs[cur][row * 64 + (((kc * 4 + lg) ^ (row & 7)) << 3)];
        o[nf] = __builtin_amdgcn_mfma_f32_16x16x32_bf16(pf, vf, o[nf], 0, 0, 0);
      }
    }
    __builtin_amdgcn_s_setprio(0);
  }

  // key 576 (the 577th key) analytic correction: s = q . k576 per q-row
  {
    const bf16* k576 = kbq + ((size_t)bh * kTok + 576) * 64;
    bf16x8 ka = *(const bf16x8*)(k576 + lg * 8);
    bf16x8 kb2 = *(const bf16x8*)(k576 + 32 + lg * 8);
    float part = 0.f;
#pragma unroll
    for (int j = 0; j < 8; ++j)
      part += (float)qf[0][j] * (float)ka[j] + (float)qf[1][j] * (float)kb2[j];
    part += __shfl_xor(part, 16);
    part += __shfl_xor(part, 32);          // s for q-row (w*16 + lr), uniform over lg
    float v576[4];
#pragma unroll
    for (int nf = 0; nf < 4; ++nf)
      v576[nf] = (float)vtb[((size_t)bh * 64 + nf * 16 + lr) * kTok + 576];
#pragma unroll
    for (int r = 0; r < 4; ++r) {
      float p = __expf(__shfl(part, lg * 4 + r));   // row lg*4+r held by lane lr==lg*4+r
      den[r] += p;
#pragma unroll
      for (int nf = 0; nf < 4; ++nf) o[nf][r] += p * v576[nf];
    }
  }

  // epilogue: normalize by den, single bf16 output
  const int b = bh / 12, h = bh % 12;
#pragma unroll
  for (int r = 0; r < 4; ++r) {
    const int tok = q0 + w * 16 + lg * 4 + r;
    if (tok > 576) continue;
    const float inv = 1.0f / den[r];
    const size_t rowb = ((size_t)(b * kNtok + tok)) * kC + h * 64;
#pragma unroll
    for (int nf = 0; nf < 4; ++nf)
      aoh[rowb + nf * 16 + lr] = (bf16)(o[nf][r] * inv);
  }
}

// ---------------- proj GEMM: r7 template, single-A, BK=64, 8 waves --------------
__global__ __launch_bounds__(512, 4) void proj_gemm_kernel(
    const bf16* __restrict__ ah, const bf16* __restrict__ bw,
    const float* __restrict__ bias, float* __restrict__ out) {
  __shared__ __align__(16) char smem[65536];
  bf16* AsB = (bf16*)smem;
  bf16* BsB = (bf16*)(smem + 32768);
  const int tid = (int)threadIdx.x;
  const int l = tid & 63, w = tid >> 6;
  const int lr = l & 15, lg = l >> 4;
  const int wr = (w & 3) * 32, wc = (w >> 2) * 64;

  const int lid = swz_lid((int)blockIdx.x, 6 * 73);
  const int n0 = (lid % 6) * 128, m0 = (lid / 6) * 128;

  const int srow = w * 16 + (l >> 3);
  const int gch = (l & 7) ^ ((l >> 3) & 7);
  const bf16* aG = ah + (size_t)(m0 + srow) * kC + gch * 8;
  const bf16* bG = bw + (size_t)(n0 + srow) * kC + gch * 8;

  f32x4 acc[2][4];
  const f32x4 z = {0.f, 0.f, 0.f, 0.f};
#pragma unroll
  for (int mi = 0; mi < 2; ++mi)
#pragma unroll
    for (int ni = 0; ni < 4; ++ni) acc[mi][ni] = z;

  auto STAGE = [&](int buf, int k0) {
#pragma unroll
    for (int i = 0; i < 2; ++i) {
      gl16(aG + (size_t)i * 8 * kC + k0, &AsB[buf * 8192 + (w * 16 + i * 8) * 64]);
      gl16(bG + (size_t)i * 8 * kC + k0, &BsB[buf * 8192 + (w * 16 + i * 8) * 64]);
    }
  };
  auto COMPUTE = [&](int buf) {
    __builtin_amdgcn_s_setprio(1);
#pragma unroll
    for (int kc = 0; kc < 2; ++kc) {
      bf16x8 af[2], bfr[4];
#pragma unroll
      for (int ni = 0; ni < 4; ++ni) {
        int row = wc + ni * 16 + lr;
        bfr[ni] = *(const bf16x8*)&BsB[buf * 8192 + row * 64 + (((kc * 4 + lg) ^ (lr & 7)) << 3)];
      }
#pragma unroll
      for (int mi = 0; mi < 2; ++mi) {
        int row = wr + mi * 16 + lr;
        af[mi] = *(const bf16x8*)&AsB[buf * 8192 + row * 64 + (((kc * 4 + lg) ^ (lr & 7)) << 3)];
      }
#pragma unroll
      for (int mi = 0; mi < 2; ++mi)
#pragma unroll
        for (int ni = 0; ni < 4; ++ni)
          acc[mi][ni] = __builtin_amdgcn_mfma_f32_16x16x32_bf16(af[mi], bfr[ni], acc[mi][ni], 0, 0, 0);
    }
    __builtin_amdgcn_s_setprio(0);
  };

  STAGE(0, 0);
#pragma unroll 1
  for (int t = 0; t < 11; ++t) {
    const int buf = t & 1;
    STAGE(buf ^ 1, (t + 1) * 64);
    asm volatile("s_waitcnt vmcnt(4)" ::: "memory");
    __builtin_amdgcn_sched_barrier(0);
    __builtin_amdgcn_s_barrier();
    COMPUTE(buf);
    __builtin_amdgcn_s_barrier();
    __builtin_amdgcn_sched_barrier(0);
  }
  asm volatile("s_waitcnt vmcnt(0)" ::: "memory");
  __builtin_amdgcn_sched_barrier(0);
  __builtin_amdgcn_s_barrier();
  COMPUTE(1);

  __syncthreads();
  float* tp = (float*)smem + w * 2048;
#pragma unroll
  for (int mi = 0; mi < 2; ++mi)
#pragma unroll
    for (int ni = 0; ni < 4; ++ni)
#pragma unroll
      for (int r = 0; r < 4; ++r)
        tp[(mi * 16 + lg * 4 + r) * 64 + ni * 16 + lr] = acc[mi][ni][r];

  const int c4 = lr * 4;
  const int ncol = n0 + wc + c4;
  float4 bv = *(const float4*)&bias[ncol];
#pragma unroll
  for (int i = 0; i < 8; ++i) {
    const int row = i * 4 + lg;
    const int m = m0 + wr + row;
    if (m >= kM) continue;
    float4 v4 = *(const float4*)&tp[row * 64 + c4];
    v4.x += bv.x; v4.y += bv.y; v4.z += bv.z; v4.w += bv.w;
    *(float4*)(out + (size_t)m * kC + ncol) = v4;
  }
}

// ---------------- launch ----------------
extern "C" void kernel_launch(void* const* d_in, const int* in_sizes, int n_in,
                              void* d_out, int out_size, void* d_ws, size_t ws_size,
                              hipStream_t stream) {
  const float* x = (const float*)d_in[0];
  const float* qkv_w = (const float*)d_in[1];
  const float* proj_w = (const float*)d_in[2];
  const float* proj_b = (const float*)d_in[3];
  const float* freqs = (const float*)d_in[4];
  float* out = (float*)d_out;

  static int qkv_smem_set = 0;
  if (!qkv_smem_set) {
    hipFuncSetAttribute((const void*)qkv_gemm_kernel,
                        hipFuncAttributeMaxDynamicSharedMemorySize, 131072);
    qkv_smem_set = 1;
  }

  char* p = (char*)d_ws;
  auto take = [&](size_t bytes) { char* r = p; p += (bytes + 255) & ~(size_t)255; return r; };
  float* cosT = (float*)take(221184 * 4);
  float* sinT = (float*)take(221184 * 4);
  bf16* xb   = (bf16*)take((size_t)kMpad * kC * 2);
  bf16* wqb  = (bf16*)take((size_t)2304 * kC * 2);
  bf16* pwb  = (bf16*)take((size_t)kC * kC * 2);
  bf16* qh   = (bf16*)take((size_t)kBH * kTok * 64 * 2);
  bf16* kbq  = (bf16*)take((size_t)kBH * kTok * 64 * 2);
  bf16* vb   = (bf16*)take((size_t)kBH * kTok * 64 * 2);
  bf16* vtb  = (bf16*)take((size_t)kBH * 64 * kTok * 2);
  bf16* aoh  = (bf16*)take((size_t)kMpad * kC * 2);

  prep_kernel<<<3552 + 864 + 288 + 864, 256, 0, stream>>>(
      x, qkv_w, proj_w, freqs, xb, wqb, pwb, cosT, sinT);
  qkv_gemm_kernel<<<dim3(37 * 9), 512, 131072, stream>>>(xb, wqb, cosT, sinT, qh, kbq, vb);
  vtrans_kernel<<<dim3(kBH, 10), 256, 0, stream>>>(vb, vtb);
  attn_kernel<<<dim3(5 * kBH), 512, 0, stream>>>(qh, kbq, vtb, aoh);
  proj_gemm_kernel<<<dim3(6 * 73), 512, 0, stream>>>(aoh, pwb, proj_b, out);
}

// Round 2
// 129.341 us; speedup vs baseline: 1.0306x; 1.0306x over previous
//
#include <hip/hip_runtime.h>

// RoPEAttention MI355X round 15:
//  qkv : 384x128 BK=64, 8 waves (4M x 2N, per-wave 96x64), 4 phases/K-tile,
//        m201-style two-barrier phases with lgkmcnt(0)+sched_barrier before MFMA.
//        Grid 25x18=450 -> 88% 2-round utilization (round-14's 333-block grid was
//        65% -> the +24% steady-state gain was eaten by tail quantization).
//        vmcnt ledger: vmcnt(2) end-of-ph3 (covers next ph0 reads of U0-U2),
//        vmcnt(4) in ph1 (covers ph2 reads of U3); every wait precedes a barrier
//        that precedes the dependent ds_reads (cross-wave DMA visibility).
//  attn/proj/prep/vtrans: unchanged from round 13 (118.2us config).

typedef __bf16 bf16;
typedef __bf16 bf16x4 __attribute__((ext_vector_type(4)));
typedef __bf16 bf16x8 __attribute__((ext_vector_type(8)));
typedef float f32x4 __attribute__((ext_vector_type(4)));

namespace {
constexpr int kC = 768;
constexpr int kNtok = 577;
constexpr int kM = 16 * kNtok;     // 9232
constexpr int kMpadQ = 9600;       // 25 * 384  (qkv M pad)
constexpr int kTok = 640;
constexpr int kBH = 192;
}

typedef __attribute__((address_space(3))) unsigned int as3_u32;
typedef __attribute__((address_space(1))) unsigned int as1_u32;
__device__ __forceinline__ void gl16(const bf16* g, bf16* l) {
  __builtin_amdgcn_global_load_lds((const as1_u32*)g, (as3_u32*)l, 16, 0, 0);
}

// m204 bijective XCD swizzle
__device__ __forceinline__ int swz_lid(int hid, int nwg) {
  int q = nwg >> 3, r = nwg & 7;
  int x = hid & 7, y = hid >> 3;
  int base = (x < r) ? x * (q + 1) : r * (q + 1) + (x - r) * q;
  return base + y;
}

// ---------------- fused prep: conv_x | conv_w(qkv) | conv_w(proj) | rope --------
__global__ __launch_bounds__(256) void prep_kernel(
    const float* __restrict__ x, const float* __restrict__ qkv_w,
    const float* __restrict__ proj_w, const float* __restrict__ freqs,
    bf16* __restrict__ xb, bf16* __restrict__ wqb, bf16* __restrict__ pwb,
    float* __restrict__ cosT, float* __restrict__ sinT) {
  const int bidx = (int)blockIdx.x;
  const int tid = (int)threadIdx.x;
  if (bidx < 3600) {                       // conv_x: kMpadQ*96 chunks of 8
    int idx = bidx * 256 + tid;
    int m = idx / 96, c8 = (idx % 96) * 8;
    bf16x8 o;
    if (m < kM) {
      const float* p = x + (size_t)m * kC + c8;
#pragma unroll
      for (int j = 0; j < 8; ++j) o[j] = (bf16)p[j];
    } else {
#pragma unroll
      for (int j = 0; j < 8; ++j) o[j] = (bf16)0.0f;
    }
    *(bf16x8*)(xb + (size_t)m * kC + c8) = o;
  } else if (bidx < 3600 + 864) {          // conv_w qkv: 2304*768
    int off = ((bidx - 3600) * 256 + tid) * 8;
    bf16x8 o;
#pragma unroll
    for (int j = 0; j < 8; ++j) o[j] = (bf16)qkv_w[off + j];
    *(bf16x8*)(wqb + off) = o;
  } else if (bidx < 3600 + 864 + 288) {    // conv_w proj: 768*768
    int off = ((bidx - 3600 - 864) * 256 + tid) * 8;
    bf16x8 o;
#pragma unroll
    for (int j = 0; j < 8; ++j) o[j] = (bf16)proj_w[off + j];
    *(bf16x8*)(pwb + off) = o;
  } else {                                 // rope table: 12*576*32
    int idx = (bidx - 3600 - 864 - 288) * 256 + tid;
    int f = idx & 31;
    int t = (idx >> 5) % 576;
    int h = idx / (576 * 32);
    float ang = (float)(t % 24) * freqs[h * 32 + f] + (float)(t / 24) * freqs[384 + h * 32 + f];
    float s, c;
    sincosf(ang, &s, &c);
    cosT[idx] = c;
    sinT[idx] = s;
  }
}

// ---------------- qkv GEMM 384x128, 8 waves, BK=64, two-barrier 4-phase --------
// LDS 128KB: buf b at smem+b*65536: A[384][64] (48KB) then B[128][64] (16KB).
// Stage units (2 gl16/thread each): U0={A0-127}, U1={A128-191,B0-63},
// U2={A192-255,B64-127}, U3={A256-383}. Tile t's phases stage tile t+1.
// Per-wave out: rows mih*192 + wm*48 + mi*16 (+lg*4+r), cols wn*64 + ni*16 (+lr).
__global__ __launch_bounds__(512, 2) void qkv_gemm_kernel(
    const bf16* __restrict__ xb, const bf16* __restrict__ wb,
    const float* __restrict__ cosT, const float* __restrict__ sinT,
    bf16* __restrict__ qh, bf16* __restrict__ kbq, bf16* __restrict__ vb) {
  extern __shared__ __align__(16) char smem[];
  const int tid = (int)threadIdx.x;
  const int l = tid & 63, w = tid >> 6;
  const int lr = l & 15, lg = l >> 4;
  const int wm = w >> 1, wn = w & 1;       // 4M x 2N waves
  const int w8 = w * 8;

  const int lid = swz_lid((int)blockIdx.x, 25 * 18);
  const int n0 = (lid % 18) * 128, m0 = (lid / 18) * 384;

  const int gch = (l & 7) ^ ((l >> 3) & 7);    // pre-swizzled global chunk
  const bf16* aG = xb + (size_t)(m0 + w8 + (l >> 3)) * kC + gch * 8;
  const bf16* bG = wb + (size_t)(n0 + w8 + (l >> 3)) * kC + gch * 8;

  auto Abuf = [&](int b) { return (bf16*)(smem + b * 65536); };
  auto Bbuf = [&](int b) { return (bf16*)(smem + b * 65536 + 49152); };

  auto SA = [&](int b, int k0, int c) {        // A rows [c*64, c*64+64)
    gl16(aG + (size_t)(c * 64) * kC + k0, Abuf(b) + (c * 64 + w8) * 64);
  };
  auto SB = [&](int b, int k0, int c) {        // B rows [c*64, c*64+64)
    gl16(bG + (size_t)(c * 64) * kC + k0, Bbuf(b) + (c * 64 + w8) * 64);
  };

  f32x4 acc[6][4];
  const f32x4 z = {0.f, 0.f, 0.f, 0.f};
#pragma unroll
  for (int mi = 0; mi < 6; ++mi)
#pragma unroll
    for (int ni = 0; ni < 4; ++ni) acc[mi][ni] = z;

  bf16x8 af[3][2], bf0[2][2], bf1[2][2];

  auto RDA = [&](int b, int mih) {
    const bf16* A = Abuf(b);
#pragma unroll
    for (int mi = 0; mi < 3; ++mi) {
      const int row = mih * 192 + wm * 48 + mi * 16 + lr;
#pragma unroll
      for (int kc = 0; kc < 2; ++kc)
        af[mi][kc] = *(const bf16x8*)&A[row * 64 + (((kc * 4 + lg) ^ (lr & 7)) << 3)];
    }
  };
  auto RDB = [&](int b, int nih, bf16x8 (&dst)[2][2]) {
    const bf16* Bp = Bbuf(b);
#pragma unroll
    for (int nl = 0; nl < 2; ++nl) {
      const int row = wn * 64 + nih * 32 + nl * 16 + lr;
#pragma unroll
      for (int kc = 0; kc < 2; ++kc)
        dst[nl][kc] = *(const bf16x8*)&Bp[row * 64 + (((kc * 4 + lg) ^ (lr & 7)) << 3)];
    }
  };
  auto MM = [&](int mih, int nih, bf16x8 (&bq)[2][2]) {
    __builtin_amdgcn_s_setprio(1);
#pragma unroll
    for (int kc = 0; kc < 2; ++kc)
#pragma unroll
      for (int mi = 0; mi < 3; ++mi)
#pragma unroll
        for (int nl = 0; nl < 2; ++nl)
          acc[mih * 3 + mi][nih * 2 + nl] = __builtin_amdgcn_mfma_f32_16x16x32_bf16(
              af[mi][kc], bq[nl][kc], acc[mih * 3 + mi][nih * 2 + nl], 0, 0, 0);
    __builtin_amdgcn_s_setprio(0);
  };
  auto LGKM0 = [&]() {
    asm volatile("s_waitcnt lgkmcnt(0)" ::: "memory");
    __builtin_amdgcn_sched_barrier(0);
  };
  auto BARV = [&](int n) {                     // vmcnt(n) then barrier
    if (n == 0) asm volatile("s_waitcnt vmcnt(0)" ::: "memory");
    else if (n == 2) asm volatile("s_waitcnt vmcnt(2)" ::: "memory");
    else if (n == 4) asm volatile("s_waitcnt vmcnt(4)" ::: "memory");
    __builtin_amdgcn_sched_barrier(0);
    __builtin_amdgcn_s_barrier();
    __builtin_amdgcn_sched_barrier(0);
  };
  auto BAR = [&]() {
    __builtin_amdgcn_sched_barrier(0);
    __builtin_amdgcn_s_barrier();
    __builtin_amdgcn_sched_barrier(0);
  };

  // prologue: stage tile 0 (8 loads); wait U0-U2 + barrier before first reads
  SA(0, 0, 0); SA(0, 0, 1);
  SA(0, 0, 2); SB(0, 0, 0);
  SA(0, 0, 3); SB(0, 0, 1);
  SA(0, 0, 4); SA(0, 0, 5);
  BARV(2);

#pragma unroll 1
  for (int t = 0; t < 11; ++t) {
    const int cb = t & 1, nb = cb ^ 1;
    const int k1 = (t + 1) * 64;
    // ph0: reads U0,U1,U2 (waited at prev ph3 / prologue)
    RDA(cb, 0); RDB(cb, 0, bf0); SA(nb, k1, 0); SA(nb, k1, 1);
    BAR(); LGKM0(); MM(0, 0, bf0); BAR();
    // ph1: vmcnt(4) retires U3 before ph2's reads of A256-383
    RDB(cb, 1, bf1); SA(nb, k1, 2); SB(nb, k1, 0);
    BARV(4); LGKM0(); MM(0, 1, bf1); BAR();
    // ph2
    RDA(cb, 1); SA(nb, k1, 3); SB(nb, k1, 1);
    BAR(); LGKM0(); MM(1, 1, bf1); BAR();
    // ph3: no ds_read (reuses bf0); vmcnt(2) retires next tile's U0-U2
    SA(nb, k1, 4); SA(nb, k1, 5);
    BARV(2); LGKM0(); MM(1, 0, bf0); BAR();
  }
  {  // final tile t=11 (buf 1), drain
    const int cb = 1;
    RDA(cb, 0); RDB(cb, 0, bf0);
    BAR(); LGKM0(); MM(0, 0, bf0); BAR();
    RDB(cb, 1, bf1);
    BARV(0); LGKM0(); MM(0, 1, bf1); BAR();
    RDA(cb, 1);
    BAR(); LGKM0(); MM(1, 1, bf1);
    LGKM0(); MM(1, 0, bf0);
  }

  // ---- epilogue: restage fp32 acc in LDS (12KB/wave, 2 strips of 48 rows),
  //      vectorized RoPE + coalesced stores ----
  __builtin_amdgcn_sched_barrier(0);
  __syncthreads();
  float* tp = (float*)smem + w * 3072;     // wave-private 48x64 f32 (12 KB)
  const int nbase = n0 + wn * 64;
  const int which = nbase / kC;
  const int h = (nbase % kC) >> 6;         // wave-uniform head
  bf16* dst = (which == 0) ? qh : (which == 1) ? kbq : vb;
  const float sc = (which == 0) ? 0.125f : 1.0f;
  const int c4 = lr * 4;
#pragma unroll
  for (int ch = 0; ch < 2; ++ch) {
#pragma unroll
    for (int mi = 0; mi < 3; ++mi)
#pragma unroll
      for (int ni = 0; ni < 4; ++ni)
#pragma unroll
        for (int r = 0; r < 4; ++r)
          tp[(mi * 16 + lg * 4 + r) * 64 + ni * 16 + lr] = acc[ch * 3 + mi][ni][r];
#pragma unroll
    for (int i = 0; i < 12; ++i) {
      const int row = i * 4 + lg;
      const int m = m0 + ch * 192 + wm * 48 + row;
      if (m >= kM) continue;
      float4 v4 = *(const float4*)&tp[row * 64 + c4];
      const int b = m / kNtok;
      const int tok = m - b * kNtok;
      float e0 = v4.x, o0 = v4.y, e1 = v4.z, o1 = v4.w;
      if (which < 2 && tok > 0) {
        const int tb = (h * 576 + tok - 1) * 32 + (c4 >> 1);
        float2 cc = *(const float2*)&cosT[tb];
        float2 ss = *(const float2*)&sinT[tb];
        float r0 = e0 * cc.x - o0 * ss.x, i0 = e0 * ss.x + o0 * cc.x;
        float r1 = e1 * cc.y - o1 * ss.y, i1 = e1 * ss.y + o1 * cc.y;
        e0 = r0; o0 = i0; e1 = r1; o1 = i1;
      }
      bf16x4 ov;
      ov[0] = (bf16)(e0 * sc); ov[1] = (bf16)(o0 * sc);
      ov[2] = (bf16)(e1 * sc); ov[3] = (bf16)(o1 * sc);
      *(bf16x4*)(dst + (((size_t)(b * 12 + h)) * kTok + tok) * 64 + c4) = ov;
    }
  }
}

// ---------------- V transpose ----------------
__global__ __launch_bounds__(256) void vtrans_kernel(const bf16* __restrict__ vb,
                                                     bf16* __restrict__ vtb) {
  __shared__ __align__(16) bf16 T[64][72];
  const int bh = (int)blockIdx.x, s = (int)blockIdx.y;
  const int t = (int)threadIdx.x;
  const int row = t >> 2, qr = t & 3;
  const int tok = s * 64 + row;
  bf16x8 v0, v1;
  if (tok < kNtok) {
    const bf16* p = vb + ((size_t)bh * kTok + tok) * 64 + qr * 16;
    v0 = *(const bf16x8*)p;
    v1 = *(const bf16x8*)(p + 8);
  } else {
#pragma unroll
    for (int j = 0; j < 8; ++j) { v0[j] = (bf16)0.0f; v1[j] = (bf16)0.0f; }
  }
#pragma unroll
  for (int j = 0; j < 8; ++j) {
    T[qr * 16 + j][row] = v0[j];
    T[qr * 16 + 8 + j][row] = v1[j];
  }
  __syncthreads();
  const int d = row;
  bf16x8 o0 = *(const bf16x8*)&T[d][qr * 16];
  bf16x8 o1 = *(const bf16x8*)&T[d][qr * 16 + 8];
  bf16* dst = vtb + ((size_t)bh * 64 + d) * kTok + s * 64 + qr * 16;
  *(bf16x8*)dst = o0;
  *(bf16x8*)(dst + 8) = o1;
}

// ---------------- flash attention: 9 exact K-tiles + key-576 correction ---------
__global__ __launch_bounds__(512, 8) void attn_kernel(
    const bf16* __restrict__ qh, const bf16* __restrict__ kbq, const bf16* __restrict__ vtb,
    bf16* __restrict__ aoh) {
  __shared__ __align__(16) bf16 Ks[2][64 * 64];   // 16 KB
  __shared__ __align__(16) bf16 Vs[2][64 * 64];   // 16 KB
  __shared__ __align__(16) bf16 Ps[8][16 * 64];   // 16 KB
  const int tid = (int)threadIdx.x;
  const int l = tid & 63, w = tid >> 6;           // 8 waves
  const int lr = l & 15, lg = l >> 4;

  const int lid = swz_lid((int)blockIdx.x, 5 * kBH);
  const int bh = lid / 5, qt = lid - bh * 5;      // all 5 q-tiles of a bh -> one XCD
  const int q0 = qt * 128;

  const int srow = w * 8 + (l >> 3);
  const int gch = (l & 7) ^ ((l >> 3) & 7);
  const bf16* kG = kbq + ((size_t)bh * kTok + srow) * 64 + gch * 8;
  const bf16* vG = vtb + ((size_t)bh * 64 + srow) * kTok + gch * 8;

  auto STAGE = [&](int buf, int j0) {
    gl16(kG + (size_t)j0 * 64, &Ks[buf][(w * 8) * 64]);
    gl16(vG + j0, &Vs[buf][(w * 8) * 64]);
  };

  bf16x8 qf[2];
  {
    const bf16* qp = qh + ((size_t)bh * kTok + (q0 + w * 16 + lr)) * 64 + lg * 8;
    qf[0] = *(const bf16x8*)qp;
    qf[1] = *(const bf16x8*)(qp + 32);
  }
  bf16x8 ones;
#pragma unroll
  for (int j = 0; j < 8; ++j) ones[j] = (bf16)1.0f;

  const f32x4 z = {0.f, 0.f, 0.f, 0.f};
  f32x4 o[4];
#pragma unroll
  for (int nf = 0; nf < 4; ++nf) o[nf] = z;
  f32x4 den = z;

  STAGE(0, 0);
#pragma unroll 1
  for (int jt = 0; jt < 9; ++jt) {              // 9 tiles = keys 0..575 exactly
    const int cur = jt & 1;
    __syncthreads();               // drains vmcnt(0): tile jt DMA done; prev reads done
    if (jt < 8) STAGE(cur ^ 1, (jt + 1) * 64);  // DMA overlaps compute below

    // S = Q K^T
    f32x4 s[4];
#pragma unroll
    for (int ni = 0; ni < 4; ++ni) s[ni] = z;
    __builtin_amdgcn_s_setprio(1);
#pragma unroll
    for (int kc = 0; kc < 2; ++kc) {
#pragma unroll
      for (int ni = 0; ni < 4; ++ni) {
        int row = ni * 16 + lr;
        bf16x8 kf = *(const bf16x8*)&Ks[cur][row * 64 + (((kc * 4 + lg) ^ (row & 7)) << 3)];
        s[ni] = __builtin_amdgcn_mfma_f32_16x16x32_bf16(qf[kc], kf, s[ni], 0, 0, 0);
      }
    }
    __builtin_amdgcn_s_setprio(0);

    // P = exp(S)  (no masking needed: all 64 keys of every tile are valid)
#pragma unroll
    for (int ni = 0; ni < 4; ++ni)
#pragma unroll
      for (int r = 0; r < 4; ++r) {
        float p = __expf(s[ni][r]);
        int prow = lg * 4 + r;
        int pcol = ni * 16 + lr;
        Ps[w][prow * 64 + ((((pcol >> 3) ^ (prow & 7)) & 7) << 3) + (pcol & 7)] = (bf16)p;
      }

    // O += P V ; den += P 1
    __builtin_amdgcn_s_setprio(1);
#pragma unroll
    for (int kc = 0; kc < 2; ++kc) {
      bf16x8 pf = *(const bf16x8*)&Ps[w][lr * 64 + (((kc * 4 + lg) ^ (lr & 7)) << 3)];
      den = __builtin_amdgcn_mfma_f32_16x16x32_bf16(pf, ones, den, 0, 0, 0);
#pragma unroll
      for (int nf = 0; nf < 4; ++nf) {
        int row = nf * 16 + lr;
        bf16x8 vf = *(const bf16x8*)&Vs[cur][row * 64 + (((kc * 4 + lg) ^ (row & 7)) << 3)];
        o[nf] = __builtin_amdgcn_mfma_f32_16x16x32_bf16(pf, vf, o[nf], 0, 0, 0);
      }
    }
    __builtin_amdgcn_s_setprio(0);
  }

  // key 576 (the 577th key) analytic correction: s = q . k576 per q-row
  {
    const bf16* k576 = kbq + ((size_t)bh * kTok + 576) * 64;
    bf16x8 ka = *(const bf16x8*)(k576 + lg * 8);
    bf16x8 kb2 = *(const bf16x8*)(k576 + 32 + lg * 8);
    float part = 0.f;
#pragma unroll
    for (int j = 0; j < 8; ++j)
      part += (float)qf[0][j] * (float)ka[j] + (float)qf[1][j] * (float)kb2[j];
    part += __shfl_xor(part, 16);
    part += __shfl_xor(part, 32);          // s for q-row (w*16 + lr), uniform over lg
    float v576[4];
#pragma unroll
    for (int nf = 0; nf < 4; ++nf)
      v576[nf] = (float)vtb[((size_t)bh * 64 + nf * 16 + lr) * kTok + 576];
#pragma unroll
    for (int r = 0; r < 4; ++r) {
      float p = __expf(__shfl(part, lg * 4 + r));   // row lg*4+r held by lane lr==lg*4+r
      den[r] += p;
#pragma unroll
      for (int nf = 0; nf < 4; ++nf) o[nf][r] += p * v576[nf];
    }
  }

  // epilogue: normalize by den, single bf16 output
  const int b = bh / 12, h = bh % 12;
#pragma unroll
  for (int r = 0; r < 4; ++r) {
    const int tok = q0 + w * 16 + lg * 4 + r;
    if (tok > 576) continue;
    const float inv = 1.0f / den[r];
    const size_t rowb = ((size_t)(b * kNtok + tok)) * kC + h * 64;
#pragma unroll
    for (int nf = 0; nf < 4; ++nf)
      aoh[rowb + nf * 16 + lr] = (bf16)(o[nf][r] * inv);
  }
}

// ---------------- proj GEMM: r7 template, single-A, BK=64, 8 waves --------------
__global__ __launch_bounds__(512, 4) void proj_gemm_kernel(
    const bf16* __restrict__ ah, const bf16* __restrict__ bw,
    const float* __restrict__ bias, float* __restrict__ out) {
  __shared__ __align__(16) char smem[65536];
  bf16* AsB = (bf16*)smem;
  bf16* BsB = (bf16*)(smem + 32768);
  const int tid = (int)threadIdx.x;
  const int l = tid & 63, w = tid >> 6;
  const int lr = l & 15, lg = l >> 4;
  const int wr = (w & 3) * 32, wc = (w >> 2) * 64;

  const int lid = swz_lid((int)blockIdx.x, 6 * 73);
  const int n0 = (lid % 6) * 128, m0 = (lid / 6) * 128;

  const int srow = w * 16 + (l >> 3);
  const int gch = (l & 7) ^ ((l >> 3) & 7);
  const bf16* aG = ah + (size_t)(m0 + srow) * kC + gch * 8;
  const bf16* bG = bw + (size_t)(n0 + srow) * kC + gch * 8;

  f32x4 acc[2][4];
  const f32x4 z = {0.f, 0.f, 0.f, 0.f};
#pragma unroll
  for (int mi = 0; mi < 2; ++mi)
#pragma unroll
    for (int ni = 0; ni < 4; ++ni) acc[mi][ni] = z;

  auto STAGE = [&](int buf, int k0) {
#pragma unroll
    for (int i = 0; i < 2; ++i) {
      gl16(aG + (size_t)i * 8 * kC + k0, &AsB[buf * 8192 + (w * 16 + i * 8) * 64]);
      gl16(bG + (size_t)i * 8 * kC + k0, &BsB[buf * 8192 + (w * 16 + i * 8) * 64]);
    }
  };
  auto COMPUTE = [&](int buf) {
    __builtin_amdgcn_s_setprio(1);
#pragma unroll
    for (int kc = 0; kc < 2; ++kc) {
      bf16x8 af[2], bfr[4];
#pragma unroll
      for (int ni = 0; ni < 4; ++ni) {
        int row = wc + ni * 16 + lr;
        bfr[ni] = *(const bf16x8*)&BsB[buf * 8192 + row * 64 + (((kc * 4 + lg) ^ (lr & 7)) << 3)];
      }
#pragma unroll
      for (int mi = 0; mi < 2; ++mi) {
        int row = wr + mi * 16 + lr;
        af[mi] = *(const bf16x8*)&AsB[buf * 8192 + row * 64 + (((kc * 4 + lg) ^ (lr & 7)) << 3)];
      }
#pragma unroll
      for (int mi = 0; mi < 2; ++mi)
#pragma unroll
        for (int ni = 0; ni < 4; ++ni)
          acc[mi][ni] = __builtin_amdgcn_mfma_f32_16x16x32_bf16(af[mi], bfr[ni], acc[mi][ni], 0, 0, 0);
    }
    __builtin_amdgcn_s_setprio(0);
  };

  STAGE(0, 0);
#pragma unroll 1
  for (int t = 0; t < 11; ++t) {
    const int buf = t & 1;
    STAGE(buf ^ 1, (t + 1) * 64);
    asm volatile("s_waitcnt vmcnt(4)" ::: "memory");
    __builtin_amdgcn_sched_barrier(0);
    __builtin_amdgcn_s_barrier();
    COMPUTE(buf);
    __builtin_amdgcn_s_barrier();
    __builtin_amdgcn_sched_barrier(0);
  }
  asm volatile("s_waitcnt vmcnt(0)" ::: "memory");
  __builtin_amdgcn_sched_barrier(0);
  __builtin_amdgcn_s_barrier();
  COMPUTE(1);

  __syncthreads();
  float* tp = (float*)smem + w * 2048;
#pragma unroll
  for (int mi = 0; mi < 2; ++mi)
#pragma unroll
    for (int ni = 0; ni < 4; ++ni)
#pragma unroll
      for (int r = 0; r < 4; ++r)
        tp[(mi * 16 + lg * 4 + r) * 64 + ni * 16 + lr] = acc[mi][ni][r];

  const int c4 = lr * 4;
  const int ncol = n0 + wc + c4;
  float4 bv = *(const float4*)&bias[ncol];
#pragma unroll
  for (int i = 0; i < 8; ++i) {
    const int row = i * 4 + lg;
    const int m = m0 + wr + row;
    if (m >= kM) continue;
    float4 v4 = *(const float4*)&tp[row * 64 + c4];
    v4.x += bv.x; v4.y += bv.y; v4.z += bv.z; v4.w += bv.w;
    *(float4*)(out + (size_t)m * kC + ncol) = v4;
  }
}

// ---------------- launch ----------------
extern "C" void kernel_launch(void* const* d_in, const int* in_sizes, int n_in,
                              void* d_out, int out_size, void* d_ws, size_t ws_size,
                              hipStream_t stream) {
  const float* x = (const float*)d_in[0];
  const float* qkv_w = (const float*)d_in[1];
  const float* proj_w = (const float*)d_in[2];
  const float* proj_b = (const float*)d_in[3];
  const float* freqs = (const float*)d_in[4];
  float* out = (float*)d_out;

  static int qkv_smem_set = 0;
  if (!qkv_smem_set) {
    hipFuncSetAttribute((const void*)qkv_gemm_kernel,
                        hipFuncAttributeMaxDynamicSharedMemorySize, 131072);
    qkv_smem_set = 1;
  }

  char* p = (char*)d_ws;
  auto take = [&](size_t bytes) { char* r = p; p += (bytes + 255) & ~(size_t)255; return r; };
  float* cosT = (float*)take(221184 * 4);
  float* sinT = (float*)take(221184 * 4);
  bf16* xb   = (bf16*)take((size_t)kMpadQ * kC * 2);
  bf16* wqb  = (bf16*)take((size_t)2304 * kC * 2);
  bf16* pwb  = (bf16*)take((size_t)kC * kC * 2);
  bf16* qh   = (bf16*)take((size_t)kBH * kTok * 64 * 2);
  bf16* kbq  = (bf16*)take((size_t)kBH * kTok * 64 * 2);
  bf16* vb   = (bf16*)take((size_t)kBH * kTok * 64 * 2);
  bf16* vtb  = (bf16*)take((size_t)kBH * 64 * kTok * 2);
  bf16* aoh  = (bf16*)take((size_t)9344 * kC * 2);

  prep_kernel<<<3600 + 864 + 288 + 864, 256, 0, stream>>>(
      x, qkv_w, proj_w, freqs, xb, wqb, pwb, cosT, sinT);
  qkv_gemm_kernel<<<dim3(25 * 18), 512, 131072, stream>>>(xb, wqb, cosT, sinT, qh, kbq, vb);
  vtrans_kernel<<<dim3(kBH, 10), 256, 0, stream>>>(vb, vtb);
  attn_kernel<<<dim3(5 * kBH), 512, 0, stream>>>(qh, kbq, vtb, aoh);
  proj_gemm_kernel<<<dim3(6 * 73), 512, 0, stream>>>(aoh, pwb, proj_b, out);
}

// Round 3
// 120.273 us; speedup vs baseline: 1.1083x; 1.0754x over previous
//
#include <hip/hip_runtime.h>

// RoPEAttention MI355X round 16:
//  qkv : REVERTED to round-13 exact (53.5us proven; 4-phase ports failed twice:
//        r14 65->tail, r15 64.8 steady-rate regression. 2-phase @2blk/CU stands).
//  attn: NEW 4-wave / QBLK=64 blocks. Old 8-wave: 48KB LDS -> 3 blk/CU, 960 blocks
//        over 768 slots = 62.5% tail utilization. New: 40KB LDS -> 4 blk/CU,
//        1920 blocks over 1024 slots = 94%. Per-wave math/swizzles unchanged.
//  proj/prep/vtrans: unchanged from round 13.

typedef __bf16 bf16;
typedef __bf16 bf16x4 __attribute__((ext_vector_type(4)));
typedef __bf16 bf16x8 __attribute__((ext_vector_type(8)));
typedef float f32x4 __attribute__((ext_vector_type(4)));

namespace {
constexpr int kC = 768;
constexpr int kNtok = 577;
constexpr int kM = 16 * kNtok;     // 9232
constexpr int kMpad = 9344;        // 73 * 128
constexpr int kTok = 640;
constexpr int kBH = 192;
}

typedef __attribute__((address_space(3))) unsigned int as3_u32;
typedef __attribute__((address_space(1))) unsigned int as1_u32;
__device__ __forceinline__ void gl16(const bf16* g, bf16* l) {
  __builtin_amdgcn_global_load_lds((const as1_u32*)g, (as3_u32*)l, 16, 0, 0);
}

// m204 bijective XCD swizzle
__device__ __forceinline__ int swz_lid(int hid, int nwg) {
  int q = nwg >> 3, r = nwg & 7;
  int x = hid & 7, y = hid >> 3;
  int base = (x < r) ? x * (q + 1) : r * (q + 1) + (x - r) * q;
  return base + y;
}

// ---------------- fused prep: conv_x | conv_w(qkv) | conv_w(proj) | rope --------
__global__ __launch_bounds__(256) void prep_kernel(
    const float* __restrict__ x, const float* __restrict__ qkv_w,
    const float* __restrict__ proj_w, const float* __restrict__ freqs,
    bf16* __restrict__ xb, bf16* __restrict__ wqb, bf16* __restrict__ pwb,
    float* __restrict__ cosT, float* __restrict__ sinT) {
  const int bidx = (int)blockIdx.x;
  const int tid = (int)threadIdx.x;
  if (bidx < 3504) {                       // conv_x: kMpad*96 chunks of 8
    int idx = bidx * 256 + tid;
    int m = idx / 96, c8 = (idx % 96) * 8;
    bf16x8 o;
    if (m < kM) {
      const float* p = x + (size_t)m * kC + c8;
#pragma unroll
      for (int j = 0; j < 8; ++j) o[j] = (bf16)p[j];
    } else {
#pragma unroll
      for (int j = 0; j < 8; ++j) o[j] = (bf16)0.0f;
    }
    *(bf16x8*)(xb + (size_t)m * kC + c8) = o;
  } else if (bidx < 3504 + 864) {          // conv_w qkv: 2304*768
    int off = ((bidx - 3504) * 256 + tid) * 8;
    bf16x8 o;
#pragma unroll
    for (int j = 0; j < 8; ++j) o[j] = (bf16)qkv_w[off + j];
    *(bf16x8*)(wqb + off) = o;
  } else if (bidx < 3504 + 864 + 288) {    // conv_w proj: 768*768
    int off = ((bidx - 3504 - 864) * 256 + tid) * 8;
    bf16x8 o;
#pragma unroll
    for (int j = 0; j < 8; ++j) o[j] = (bf16)proj_w[off + j];
    *(bf16x8*)(pwb + off) = o;
  } else {                                 // rope table: 12*576*32
    int idx = (bidx - 3504 - 864 - 288) * 256 + tid;
    int f = idx & 31;
    int t = (idx >> 5) % 576;
    int h = idx / (576 * 32);
    float ang = (float)(t % 24) * freqs[h * 32 + f] + (float)(t / 24) * freqs[384 + h * 32 + f];
    float s, c;
    sincosf(ang, &s, &c);
    cosT[idx] = c;
    sinT[idx] = s;
  }
}

// ---------------- qkv GEMM 128x128, 8 waves, BK=64 counted-vmcnt (r7 exact) -----
__global__ __launch_bounds__(512, 4) void qkv_gemm_kernel(
    const bf16* __restrict__ xb, const bf16* __restrict__ wb,
    const float* __restrict__ cosT, const float* __restrict__ sinT,
    bf16* __restrict__ qh, bf16* __restrict__ kbq, bf16* __restrict__ vb) {
  __shared__ __align__(16) char smem[65536];
  bf16* AsB = (bf16*)smem;             // [2][128*64]
  bf16* BsB = (bf16*)(smem + 32768);   // [2][128*64]
  const int tid = (int)threadIdx.x;
  const int l = tid & 63, w = tid >> 6;        // 8 waves
  const int lr = l & 15, lg = l >> 4;
  const int wr = (w & 3) * 32, wc = (w >> 2) * 64;   // wave tile 32x64

  const int lid = swz_lid((int)blockIdx.x, 18 * 73);
  const int n0 = (lid % 18) * 128, m0 = (lid / 18) * 128;

  const int srow = w * 16 + (l >> 3);
  const int gch = (l & 7) ^ ((l >> 3) & 7);    // pre-swizzled global chunk
  const bf16* aG = xb + (size_t)(m0 + srow) * kC + gch * 8;
  const bf16* bG = wb + (size_t)(n0 + srow) * kC + gch * 8;

  f32x4 acc[2][4];
  const f32x4 z = {0.f, 0.f, 0.f, 0.f};
#pragma unroll
  for (int mi = 0; mi < 2; ++mi)
#pragma unroll
    for (int ni = 0; ni < 4; ++ni) acc[mi][ni] = z;

  auto STAGE = [&](int buf, int k0) {
#pragma unroll
    for (int i = 0; i < 2; ++i) {
      gl16(aG + (size_t)i * 8 * kC + k0, &AsB[buf * 8192 + (w * 16 + i * 8) * 64]);
      gl16(bG + (size_t)i * 8 * kC + k0, &BsB[buf * 8192 + (w * 16 + i * 8) * 64]);
    }
  };
  auto COMPUTE = [&](int buf) {
    __builtin_amdgcn_s_setprio(1);
#pragma unroll
    for (int kc = 0; kc < 2; ++kc) {
      bf16x8 af[2], bfr[4];
#pragma unroll
      for (int ni = 0; ni < 4; ++ni) {
        int row = wc + ni * 16 + lr;
        bfr[ni] = *(const bf16x8*)&BsB[buf * 8192 + row * 64 + (((kc * 4 + lg) ^ (lr & 7)) << 3)];
      }
#pragma unroll
      for (int mi = 0; mi < 2; ++mi) {
        int row = wr + mi * 16 + lr;
        af[mi] = *(const bf16x8*)&AsB[buf * 8192 + row * 64 + (((kc * 4 + lg) ^ (lr & 7)) << 3)];
      }
#pragma unroll
      for (int mi = 0; mi < 2; ++mi)
#pragma unroll
        for (int ni = 0; ni < 4; ++ni)
          acc[mi][ni] = __builtin_amdgcn_mfma_f32_16x16x32_bf16(af[mi], bfr[ni], acc[mi][ni], 0, 0, 0);
    }
    __builtin_amdgcn_s_setprio(0);
  };

  STAGE(0, 0);
#pragma unroll 1
  for (int t = 0; t < 11; ++t) {
    const int buf = t & 1;
    STAGE(buf ^ 1, (t + 1) * 64);
    asm volatile("s_waitcnt vmcnt(4)" ::: "memory");
    __builtin_amdgcn_sched_barrier(0);
    __builtin_amdgcn_s_barrier();
    COMPUTE(buf);
    __builtin_amdgcn_s_barrier();
    __builtin_amdgcn_sched_barrier(0);
  }
  asm volatile("s_waitcnt vmcnt(0)" ::: "memory");
  __builtin_amdgcn_sched_barrier(0);
  __builtin_amdgcn_s_barrier();
  COMPUTE(1);

  // ---- epilogue: restage fp32 acc in LDS, vectorized RoPE + coalesced stores ----
  __syncthreads();
  float* tp = (float*)smem + w * 2048;   // wave-private 32x64 f32 tile (8 KB)
#pragma unroll
  for (int mi = 0; mi < 2; ++mi)
#pragma unroll
    for (int ni = 0; ni < 4; ++ni)
#pragma unroll
      for (int r = 0; r < 4; ++r)
        tp[(mi * 16 + lg * 4 + r) * 64 + ni * 16 + lr] = acc[mi][ni][r];

  const int which = n0 / kC;
  const int h = ((n0 + wc) % kC) >> 6;             // wave-uniform head
  bf16* dst = (which == 0) ? qh : (which == 1) ? kbq : vb;
  const float sc = (which == 0) ? 0.125f : 1.0f;
  const int c4 = lr * 4;
#pragma unroll
  for (int i = 0; i < 8; ++i) {
    const int row = i * 4 + lg;
    const int m = m0 + wr + row;
    if (m >= kM) continue;
    float4 v4 = *(const float4*)&tp[row * 64 + c4];
    const int b = m / kNtok;
    const int tok = m - b * kNtok;
    float e0 = v4.x, o0 = v4.y, e1 = v4.z, o1 = v4.w;
    if (which < 2 && tok > 0) {
      const int tb = (h * 576 + tok - 1) * 32 + (c4 >> 1);
      float2 cc = *(const float2*)&cosT[tb];
      float2 ss = *(const float2*)&sinT[tb];
      float r0 = e0 * cc.x - o0 * ss.x, i0 = e0 * ss.x + o0 * cc.x;
      float r1 = e1 * cc.y - o1 * ss.y, i1 = e1 * ss.y + o1 * cc.y;
      e0 = r0; o0 = i0; e1 = r1; o1 = i1;
    }
    bf16x4 ov;
    ov[0] = (bf16)(e0 * sc); ov[1] = (bf16)(o0 * sc);
    ov[2] = (bf16)(e1 * sc); ov[3] = (bf16)(o1 * sc);
    *(bf16x4*)(dst + (((size_t)(b * 12 + h)) * kTok + tok) * 64 + c4) = ov;
  }
}

// ---------------- V transpose ----------------
__global__ __launch_bounds__(256) void vtrans_kernel(const bf16* __restrict__ vb,
                                                     bf16* __restrict__ vtb) {
  __shared__ __align__(16) bf16 T[64][72];
  const int bh = (int)blockIdx.x, s = (int)blockIdx.y;
  const int t = (int)threadIdx.x;
  const int row = t >> 2, qr = t & 3;
  const int tok = s * 64 + row;
  bf16x8 v0, v1;
  if (tok < kNtok) {
    const bf16* p = vb + ((size_t)bh * kTok + tok) * 64 + qr * 16;
    v0 = *(const bf16x8*)p;
    v1 = *(const bf16x8*)(p + 8);
  } else {
#pragma unroll
    for (int j = 0; j < 8; ++j) { v0[j] = (bf16)0.0f; v1[j] = (bf16)0.0f; }
  }
#pragma unroll
  for (int j = 0; j < 8; ++j) {
    T[qr * 16 + j][row] = v0[j];
    T[qr * 16 + 8 + j][row] = v1[j];
  }
  __syncthreads();
  const int d = row;
  bf16x8 o0 = *(const bf16x8*)&T[d][qr * 16];
  bf16x8 o1 = *(const bf16x8*)&T[d][qr * 16 + 8];
  bf16* dst = vtb + ((size_t)bh * 64 + d) * kTok + s * 64 + qr * 16;
  *(bf16x8*)dst = o0;
  *(bf16x8*)(dst + 8) = o1;
}

// ---------------- flash attention: 4 waves, QBLK=64, 9 K-tiles + key-576 --------
// 40KB LDS -> 4 blocks/CU; grid 1920 over 1024 slots = 94% tail utilization
// (old 8-wave/48KB: 3 blk/CU, 960 over 768 = 62.5%). Per-wave math unchanged.
__global__ __launch_bounds__(256, 4) void attn_kernel(
    const bf16* __restrict__ qh, const bf16* __restrict__ kbq, const bf16* __restrict__ vtb,
    bf16* __restrict__ aoh) {
  __shared__ __align__(16) bf16 Ks[2][64 * 64];   // 16 KB
  __shared__ __align__(16) bf16 Vs[2][64 * 64];   // 16 KB
  __shared__ __align__(16) bf16 Ps[4][16 * 64];   // 8 KB
  const int tid = (int)threadIdx.x;
  const int l = tid & 63, w = tid >> 6;           // 4 waves
  const int lr = l & 15, lg = l >> 4;

  const int lid = swz_lid((int)blockIdx.x, 10 * kBH);
  const int bh = lid / 10, qt = lid - bh * 10;    // all 10 q-tiles of a bh -> one XCD
  const int q0 = qt * 64;

  const int srow = w * 16 + (l >> 3);
  const int gch = (l & 7) ^ ((l >> 3) & 7);
  const bf16* kG = kbq + ((size_t)bh * kTok + srow) * 64 + gch * 8;
  const bf16* vG = vtb + ((size_t)bh * 64 + srow) * kTok + gch * 8;

  auto STAGE = [&](int buf, int j0) {
    gl16(kG + (size_t)j0 * 64, &Ks[buf][(w * 16) * 64]);
    gl16(kG + (size_t)j0 * 64 + 8 * 64, &Ks[buf][(w * 16 + 8) * 64]);
    gl16(vG + j0, &Vs[buf][(w * 16) * 64]);
    gl16(vG + j0 + (size_t)8 * kTok, &Vs[buf][(w * 16 + 8) * 64]);
  };

  bf16x8 qf[2];
  {
    const bf16* qp = qh + ((size_t)bh * kTok + (q0 + w * 16 + lr)) * 64 + lg * 8;
    qf[0] = *(const bf16x8*)qp;
    qf[1] = *(const bf16x8*)(qp + 32);
  }
  bf16x8 ones;
#pragma unroll
  for (int j = 0; j < 8; ++j) ones[j] = (bf16)1.0f;

  const f32x4 z = {0.f, 0.f, 0.f, 0.f};
  f32x4 o[4];
#pragma unroll
  for (int nf = 0; nf < 4; ++nf) o[nf] = z;
  f32x4 den = z;

  STAGE(0, 0);
#pragma unroll 1
  for (int jt = 0; jt < 9; ++jt) {              // 9 tiles = keys 0..575 exactly
    const int cur = jt & 1;
    __syncthreads();               // drains vmcnt(0): tile jt DMA done; prev reads done
    if (jt < 8) STAGE(cur ^ 1, (jt + 1) * 64);  // DMA overlaps compute below

    // S = Q K^T
    f32x4 s[4];
#pragma unroll
    for (int ni = 0; ni < 4; ++ni) s[ni] = z;
    __builtin_amdgcn_s_setprio(1);
#pragma unroll
    for (int kc = 0; kc < 2; ++kc) {
#pragma unroll
      for (int ni = 0; ni < 4; ++ni) {
        int row = ni * 16 + lr;
        bf16x8 kf = *(const bf16x8*)&Ks[cur][row * 64 + (((kc * 4 + lg) ^ (row & 7)) << 3)];
        s[ni] = __builtin_amdgcn_mfma_f32_16x16x32_bf16(qf[kc], kf, s[ni], 0, 0, 0);
      }
    }
    __builtin_amdgcn_s_setprio(0);

    // P = exp(S)  (no masking needed: all 64 keys of every tile are valid)
#pragma unroll
    for (int ni = 0; ni < 4; ++ni)
#pragma unroll
      for (int r = 0; r < 4; ++r) {
        float p = __expf(s[ni][r]);
        int prow = lg * 4 + r;
        int pcol = ni * 16 + lr;
        Ps[w][prow * 64 + ((((pcol >> 3) ^ (prow & 7)) & 7) << 3) + (pcol & 7)] = (bf16)p;
      }

    // O += P V ; den += P 1
    __builtin_amdgcn_s_setprio(1);
#pragma unroll
    for (int kc = 0; kc < 2; ++kc) {
      bf16x8 pf = *(const bf16x8*)&Ps[w][lr * 64 + (((kc * 4 + lg) ^ (lr & 7)) << 3)];
      den = __builtin_amdgcn_mfma_f32_16x16x32_bf16(pf, ones, den, 0, 0, 0);
#pragma unroll
      for (int nf = 0; nf < 4; ++nf) {
        int row = nf * 16 + lr;
        bf16x8 vf = *(const bf16x8*)&Vs[cur][row * 64 + (((kc * 4 + lg) ^ (row & 7)) << 3)];
        o[nf] = __builtin_amdgcn_mfma_f32_16x16x32_bf16(pf, vf, o[nf], 0, 0, 0);
      }
    }
    __builtin_amdgcn_s_setprio(0);
  }

  // key 576 (the 577th key) analytic correction: s = q . k576 per q-row
  {
    const bf16* k576 = kbq + ((size_t)bh * kTok + 576) * 64;
    bf16x8 ka = *(const bf16x8*)(k576 + lg * 8);
    bf16x8 kb2 = *(const bf16x8*)(k576 + 32 + lg * 8);
    float part = 0.f;
#pragma unroll
    for (int j = 0; j < 8; ++j)
      part += (float)qf[0][j] * (float)ka[j] + (float)qf[1][j] * (float)kb2[j];
    part += __shfl_xor(part, 16);
    part += __shfl_xor(part, 32);          // s for q-row (w*16 + lr), uniform over lg
    float v576[4];
#pragma unroll
    for (int nf = 0; nf < 4; ++nf)
      v576[nf] = (float)vtb[((size_t)bh * 64 + nf * 16 + lr) * kTok + 576];
#pragma unroll
    for (int r = 0; r < 4; ++r) {
      float p = __expf(__shfl(part, lg * 4 + r));   // row lg*4+r held by lane lr==lg*4+r
      den[r] += p;
#pragma unroll
      for (int nf = 0; nf < 4; ++nf) o[nf][r] += p * v576[nf];
    }
  }

  // epilogue: normalize by den, single bf16 output
  const int b = bh / 12, h = bh % 12;
#pragma unroll
  for (int r = 0; r < 4; ++r) {
    const int tok = q0 + w * 16 + lg * 4 + r;
    if (tok > 576) continue;
    const float inv = 1.0f / den[r];
    const size_t rowb = ((size_t)(b * kNtok + tok)) * kC + h * 64;
#pragma unroll
    for (int nf = 0; nf < 4; ++nf)
      aoh[rowb + nf * 16 + lr] = (bf16)(o[nf][r] * inv);
  }
}

// ---------------- proj GEMM: r7 template, single-A, BK=64, 8 waves --------------
__global__ __launch_bounds__(512, 4) void proj_gemm_kernel(
    const bf16* __restrict__ ah, const bf16* __restrict__ bw,
    const float* __restrict__ bias, float* __restrict__ out) {
  __shared__ __align__(16) char smem[65536];
  bf16* AsB = (bf16*)smem;
  bf16* BsB = (bf16*)(smem + 32768);
  const int tid = (int)threadIdx.x;
  const int l = tid & 63, w = tid >> 6;
  const int lr = l & 15, lg = l >> 4;
  const int wr = (w & 3) * 32, wc = (w >> 2) * 64;

  const int lid = swz_lid((int)blockIdx.x, 6 * 73);
  const int n0 = (lid % 6) * 128, m0 = (lid / 6) * 128;

  const int srow = w * 16 + (l >> 3);
  const int gch = (l & 7) ^ ((l >> 3) & 7);
  const bf16* aG = ah + (size_t)(m0 + srow) * kC + gch * 8;
  const bf16* bG = bw + (size_t)(n0 + srow) * kC + gch * 8;

  f32x4 acc[2][4];
  const f32x4 z = {0.f, 0.f, 0.f, 0.f};
#pragma unroll
  for (int mi = 0; mi < 2; ++mi)
#pragma unroll
    for (int ni = 0; ni < 4; ++ni) acc[mi][ni] = z;

  auto STAGE = [&](int buf, int k0) {
#pragma unroll
    for (int i = 0; i < 2; ++i) {
      gl16(aG + (size_t)i * 8 * kC + k0, &AsB[buf * 8192 + (w * 16 + i * 8) * 64]);
      gl16(bG + (size_t)i * 8 * kC + k0, &BsB[buf * 8192 + (w * 16 + i * 8) * 64]);
    }
  };
  auto COMPUTE = [&](int buf) {
    __builtin_amdgcn_s_setprio(1);
#pragma unroll
    for (int kc = 0; kc < 2; ++kc) {
      bf16x8 af[2], bfr[4];
#pragma unroll
      for (int ni = 0; ni < 4; ++ni) {
        int row = wc + ni * 16 + lr;
        bfr[ni] = *(const bf16x8*)&BsB[buf * 8192 + row * 64 + (((kc * 4 + lg) ^ (lr & 7)) << 3)];
      }
#pragma unroll
      for (int mi = 0; mi < 2; ++mi) {
        int row = wr + mi * 16 + lr;
        af[mi] = *(const bf16x8*)&AsB[buf * 8192 + row * 64 + (((kc * 4 + lg) ^ (lr & 7)) << 3)];
      }
#pragma unroll
      for (int mi = 0; mi < 2; ++mi)
#pragma unroll
        for (int ni = 0; ni < 4; ++ni)
          acc[mi][ni] = __builtin_amdgcn_mfma_f32_16x16x32_bf16(af[mi], bfr[ni], acc[mi][ni], 0, 0, 0);
    }
    __builtin_amdgcn_s_setprio(0);
  };

  STAGE(0, 0);
#pragma unroll 1
  for (int t = 0; t < 11; ++t) {
    const int buf = t & 1;
    STAGE(buf ^ 1, (t + 1) * 64);
    asm volatile("s_waitcnt vmcnt(4)" ::: "memory");
    __builtin_amdgcn_sched_barrier(0);
    __builtin_amdgcn_s_barrier();
    COMPUTE(buf);
    __builtin_amdgcn_s_barrier();
    __builtin_amdgcn_sched_barrier(0);
  }
  asm volatile("s_waitcnt vmcnt(0)" ::: "memory");
  __builtin_amdgcn_sched_barrier(0);
  __builtin_amdgcn_s_barrier();
  COMPUTE(1);

  __syncthreads();
  float* tp = (float*)smem + w * 2048;
#pragma unroll
  for (int mi = 0; mi < 2; ++mi)
#pragma unroll
    for (int ni = 0; ni < 4; ++ni)
#pragma unroll
      for (int r = 0; r < 4; ++r)
        tp[(mi * 16 + lg * 4 + r) * 64 + ni * 16 + lr] = acc[mi][ni][r];

  const int c4 = lr * 4;
  const int ncol = n0 + wc + c4;
  float4 bv = *(const float4*)&bias[ncol];
#pragma unroll
  for (int i = 0; i < 8; ++i) {
    const int row = i * 4 + lg;
    const int m = m0 + wr + row;
    if (m >= kM) continue;
    float4 v4 = *(const float4*)&tp[row * 64 + c4];
    v4.x += bv.x; v4.y += bv.y; v4.z += bv.z; v4.w += bv.w;
    *(float4*)(out + (size_t)m * kC + ncol) = v4;
  }
}

// ---------------- launch ----------------
extern "C" void kernel_launch(void* const* d_in, const int* in_sizes, int n_in,
                              void* d_out, int out_size, void* d_ws, size_t ws_size,
                              hipStream_t stream) {
  const float* x = (const float*)d_in[0];
  const float* qkv_w = (const float*)d_in[1];
  const float* proj_w = (const float*)d_in[2];
  const float* proj_b = (const float*)d_in[3];
  const float* freqs = (const float*)d_in[4];
  float* out = (float*)d_out;

  char* p = (char*)d_ws;
  auto take = [&](size_t bytes) { char* r = p; p += (bytes + 255) & ~(size_t)255; return r; };
  float* cosT = (float*)take(221184 * 4);
  float* sinT = (float*)take(221184 * 4);
  bf16* xb   = (bf16*)take((size_t)kMpad * kC * 2);
  bf16* wqb  = (bf16*)take((size_t)2304 * kC * 2);
  bf16* pwb  = (bf16*)take((size_t)kC * kC * 2);
  bf16* qh   = (bf16*)take((size_t)kBH * kTok * 64 * 2);
  bf16* kbq  = (bf16*)take((size_t)kBH * kTok * 64 * 2);
  bf16* vb   = (bf16*)take((size_t)kBH * kTok * 64 * 2);
  bf16* vtb  = (bf16*)take((size_t)kBH * 64 * kTok * 2);
  bf16* aoh  = (bf16*)take((size_t)kMpad * kC * 2);

  prep_kernel<<<3504 + 864 + 288 + 864, 256, 0, stream>>>(
      x, qkv_w, proj_w, freqs, xb, wqb, pwb, cosT, sinT);
  qkv_gemm_kernel<<<dim3(18 * 73), 512, 0, stream>>>(xb, wqb, cosT, sinT, qh, kbq, vb);
  vtrans_kernel<<<dim3(kBH, 10), 256, 0, stream>>>(vb, vtb);
  attn_kernel<<<dim3(10 * kBH), 256, 0, stream>>>(qh, kbq, vtb, aoh);
  proj_gemm_kernel<<<dim3(6 * 73), 512, 0, stream>>>(aoh, pwb, proj_b, out);
}

// Round 5
// 111.102 us; speedup vs baseline: 1.1998x; 1.0825x over previous
//
#include <hip/hip_runtime.h>

// RoPEAttention MI355X round 18:
//  qkv : r13 2-phase 128x128 core (proven 53.5us) + FUSED V-transpose epilogue.
//        r17 bug: V LDS restage used stride 63 for 64 cols -> (row,63) aliased
//        (row+1,0). Fixed: bf16 tile stride 65 (no aliasing, <=2-way banks).
//  attn: r13 8-wave QBLK=128 (proven).
//  proj/prep: unchanged from round 13. vtrans kernel deleted.

typedef __bf16 bf16;
typedef __bf16 bf16x4 __attribute__((ext_vector_type(4)));
typedef __bf16 bf16x8 __attribute__((ext_vector_type(8)));
typedef float f32x4 __attribute__((ext_vector_type(4)));

namespace {
constexpr int kC = 768;
constexpr int kNtok = 577;
constexpr int kM = 16 * kNtok;     // 9232
constexpr int kMpad = 9344;        // 73 * 128
constexpr int kTok = 640;
constexpr int kBH = 192;
}

typedef __attribute__((address_space(3))) unsigned int as3_u32;
typedef __attribute__((address_space(1))) unsigned int as1_u32;
__device__ __forceinline__ void gl16(const bf16* g, bf16* l) {
  __builtin_amdgcn_global_load_lds((const as1_u32*)g, (as3_u32*)l, 16, 0, 0);
}

// m204 bijective XCD swizzle
__device__ __forceinline__ int swz_lid(int hid, int nwg) {
  int q = nwg >> 3, r = nwg & 7;
  int x = hid & 7, y = hid >> 3;
  int base = (x < r) ? x * (q + 1) : r * (q + 1) + (x - r) * q;
  return base + y;
}

// ---------------- fused prep: conv_x | conv_w(qkv) | conv_w(proj) | rope --------
__global__ __launch_bounds__(256) void prep_kernel(
    const float* __restrict__ x, const float* __restrict__ qkv_w,
    const float* __restrict__ proj_w, const float* __restrict__ freqs,
    bf16* __restrict__ xb, bf16* __restrict__ wqb, bf16* __restrict__ pwb,
    float* __restrict__ cosT, float* __restrict__ sinT) {
  const int bidx = (int)blockIdx.x;
  const int tid = (int)threadIdx.x;
  if (bidx < 3504) {                       // conv_x: kMpad*96 chunks of 8
    int idx = bidx * 256 + tid;
    int m = idx / 96, c8 = (idx % 96) * 8;
    bf16x8 o;
    if (m < kM) {
      const float* p = x + (size_t)m * kC + c8;
#pragma unroll
      for (int j = 0; j < 8; ++j) o[j] = (bf16)p[j];
    } else {
#pragma unroll
      for (int j = 0; j < 8; ++j) o[j] = (bf16)0.0f;
    }
    *(bf16x8*)(xb + (size_t)m * kC + c8) = o;
  } else if (bidx < 3504 + 864) {          // conv_w qkv: 2304*768
    int off = ((bidx - 3504) * 256 + tid) * 8;
    bf16x8 o;
#pragma unroll
    for (int j = 0; j < 8; ++j) o[j] = (bf16)qkv_w[off + j];
    *(bf16x8*)(wqb + off) = o;
  } else if (bidx < 3504 + 864 + 288) {    // conv_w proj: 768*768
    int off = ((bidx - 3504 - 864) * 256 + tid) * 8;
    bf16x8 o;
#pragma unroll
    for (int j = 0; j < 8; ++j) o[j] = (bf16)proj_w[off + j];
    *(bf16x8*)(pwb + off) = o;
  } else {                                 // rope table: 12*576*32
    int idx = (bidx - 3504 - 864 - 288) * 256 + tid;
    int f = idx & 31;
    int t = (idx >> 5) % 576;
    int h = idx / (576 * 32);
    float ang = (float)(t % 24) * freqs[h * 32 + f] + (float)(t / 24) * freqs[384 + h * 32 + f];
    float s, c;
    sincosf(ang, &s, &c);
    cosT[idx] = c;
    sinT[idx] = s;
  }
}

// ---------------- qkv GEMM 128x128, 8 waves, BK=64 counted-vmcnt (r7 exact) -----
// Epilogue: Q/K -> RoPE + [bh][tok][d] stores; V -> fused transpose to [bh][d][tok].
__global__ __launch_bounds__(512, 4) void qkv_gemm_kernel(
    const bf16* __restrict__ xb, const bf16* __restrict__ wb,
    const float* __restrict__ cosT, const float* __restrict__ sinT,
    bf16* __restrict__ qh, bf16* __restrict__ kbq, bf16* __restrict__ vtb) {
  __shared__ __align__(16) char smem[65536];
  bf16* AsB = (bf16*)smem;             // [2][128*64]
  bf16* BsB = (bf16*)(smem + 32768);   // [2][128*64]
  const int tid = (int)threadIdx.x;
  const int l = tid & 63, w = tid >> 6;        // 8 waves
  const int lr = l & 15, lg = l >> 4;
  const int wr = (w & 3) * 32, wc = (w >> 2) * 64;   // wave tile 32x64

  const int lid = swz_lid((int)blockIdx.x, 18 * 73);
  const int n0 = (lid % 18) * 128, m0 = (lid / 18) * 128;

  const int srow = w * 16 + (l >> 3);
  const int gch = (l & 7) ^ ((l >> 3) & 7);    // pre-swizzled global chunk
  const bf16* aG = xb + (size_t)(m0 + srow) * kC + gch * 8;
  const bf16* bG = wb + (size_t)(n0 + srow) * kC + gch * 8;

  f32x4 acc[2][4];
  const f32x4 z = {0.f, 0.f, 0.f, 0.f};
#pragma unroll
  for (int mi = 0; mi < 2; ++mi)
#pragma unroll
    for (int ni = 0; ni < 4; ++ni) acc[mi][ni] = z;

  auto STAGE = [&](int buf, int k0) {
#pragma unroll
    for (int i = 0; i < 2; ++i) {
      gl16(aG + (size_t)i * 8 * kC + k0, &AsB[buf * 8192 + (w * 16 + i * 8) * 64]);
      gl16(bG + (size_t)i * 8 * kC + k0, &BsB[buf * 8192 + (w * 16 + i * 8) * 64]);
    }
  };
  auto COMPUTE = [&](int buf) {
    __builtin_amdgcn_s_setprio(1);
#pragma unroll
    for (int kc = 0; kc < 2; ++kc) {
      bf16x8 af[2], bfr[4];
#pragma unroll
      for (int ni = 0; ni < 4; ++ni) {
        int row = wc + ni * 16 + lr;
        bfr[ni] = *(const bf16x8*)&BsB[buf * 8192 + row * 64 + (((kc * 4 + lg) ^ (lr & 7)) << 3)];
      }
#pragma unroll
      for (int mi = 0; mi < 2; ++mi) {
        int row = wr + mi * 16 + lr;
        af[mi] = *(const bf16x8*)&AsB[buf * 8192 + row * 64 + (((kc * 4 + lg) ^ (lr & 7)) << 3)];
      }
#pragma unroll
      for (int mi = 0; mi < 2; ++mi)
#pragma unroll
        for (int ni = 0; ni < 4; ++ni)
          acc[mi][ni] = __builtin_amdgcn_mfma_f32_16x16x32_bf16(af[mi], bfr[ni], acc[mi][ni], 0, 0, 0);
    }
    __builtin_amdgcn_s_setprio(0);
  };

  STAGE(0, 0);
#pragma unroll 1
  for (int t = 0; t < 11; ++t) {
    const int buf = t & 1;
    STAGE(buf ^ 1, (t + 1) * 64);
    asm volatile("s_waitcnt vmcnt(4)" ::: "memory");
    __builtin_amdgcn_sched_barrier(0);
    __builtin_amdgcn_s_barrier();
    COMPUTE(buf);
    __builtin_amdgcn_s_barrier();
    __builtin_amdgcn_sched_barrier(0);
  }
  asm volatile("s_waitcnt vmcnt(0)" ::: "memory");
  __builtin_amdgcn_sched_barrier(0);
  __builtin_amdgcn_s_barrier();
  COMPUTE(1);

  // ---- epilogue ----
  __syncthreads();
  const int which = n0 / kC;
  const int h = ((n0 + wc) % kC) >> 6;             // wave-uniform head

  if (which == 2) {
    // Fused V transpose: acc -> wave-private bf16 LDS tile [32][stride 65]
    // (no aliasing: col<=63<65; <=2-way banks on column reads), then
    // coalesced [d][tok] stores (lanes 0-31 even d, 32-63 odd d).
    bf16* tq = (bf16*)smem + w * 4096;             // 8KB region, uses 4160B
#pragma unroll
    for (int mi = 0; mi < 2; ++mi)
#pragma unroll
      for (int ni = 0; ni < 4; ++ni)
#pragma unroll
        for (int r = 0; r < 4; ++r)
          tq[(mi * 16 + lg * 4 + r) * 65 + ni * 16 + lr] = (bf16)acc[mi][ni][r];
    const int tokrow = l & 31;
    const int dhalf = l >> 5;                      // 0 or 1
    const int m = m0 + wr + tokrow;
    if (m < kM) {
      const int b = m / kNtok;
      const int tok = m - b * kNtok;
      bf16* vdst = vtb + ((size_t)(b * 12 + h) * 64 + dhalf) * kTok + tok;
#pragma unroll
      for (int it = 0; it < 32; ++it)
        vdst[(size_t)(it * 2) * kTok] = tq[tokrow * 65 + it * 2 + dhalf];
    }
  } else {
    // Q/K: restage fp32 acc in LDS, vectorized RoPE + coalesced stores
    float* tp = (float*)smem + w * 2048;           // wave-private 32x64 f32 (8 KB)
#pragma unroll
    for (int mi = 0; mi < 2; ++mi)
#pragma unroll
      for (int ni = 0; ni < 4; ++ni)
#pragma unroll
        for (int r = 0; r < 4; ++r)
          tp[(mi * 16 + lg * 4 + r) * 64 + ni * 16 + lr] = acc[mi][ni][r];

    bf16* dst = (which == 0) ? qh : kbq;
    const float sc = (which == 0) ? 0.125f : 1.0f;
    const int c4 = lr * 4;
#pragma unroll
    for (int i = 0; i < 8; ++i) {
      const int row = i * 4 + lg;
      const int m = m0 + wr + row;
      if (m >= kM) continue;
      float4 v4 = *(const float4*)&tp[row * 64 + c4];
      const int b = m / kNtok;
      const int tok = m - b * kNtok;
      float e0 = v4.x, o0 = v4.y, e1 = v4.z, o1 = v4.w;
      if (tok > 0) {
        const int tb = (h * 576 + tok - 1) * 32 + (c4 >> 1);
        float2 cc = *(const float2*)&cosT[tb];
        float2 ss = *(const float2*)&sinT[tb];
        float r0 = e0 * cc.x - o0 * ss.x, i0 = e0 * ss.x + o0 * cc.x;
        float r1 = e1 * cc.y - o1 * ss.y, i1 = e1 * ss.y + o1 * cc.y;
        e0 = r0; o0 = i0; e1 = r1; o1 = i1;
      }
      bf16x4 ov;
      ov[0] = (bf16)(e0 * sc); ov[1] = (bf16)(o0 * sc);
      ov[2] = (bf16)(e1 * sc); ov[3] = (bf16)(o1 * sc);
      *(bf16x4*)(dst + (((size_t)(b * 12 + h)) * kTok + tok) * 64 + c4) = ov;
    }
  }
}

// ---------------- flash attention: 8 waves, 9 exact K-tiles + key-576 -----------
__global__ __launch_bounds__(512, 8) void attn_kernel(
    const bf16* __restrict__ qh, const bf16* __restrict__ kbq, const bf16* __restrict__ vtb,
    bf16* __restrict__ aoh) {
  __shared__ __align__(16) bf16 Ks[2][64 * 64];   // 16 KB
  __shared__ __align__(16) bf16 Vs[2][64 * 64];   // 16 KB
  __shared__ __align__(16) bf16 Ps[8][16 * 64];   // 16 KB
  const int tid = (int)threadIdx.x;
  const int l = tid & 63, w = tid >> 6;           // 8 waves
  const int lr = l & 15, lg = l >> 4;

  const int lid = swz_lid((int)blockIdx.x, 5 * kBH);
  const int bh = lid / 5, qt = lid - bh * 5;      // all 5 q-tiles of a bh -> one XCD
  const int q0 = qt * 128;

  const int srow = w * 8 + (l >> 3);
  const int gch = (l & 7) ^ ((l >> 3) & 7);
  const bf16* kG = kbq + ((size_t)bh * kTok + srow) * 64 + gch * 8;
  const bf16* vG = vtb + ((size_t)bh * 64 + srow) * kTok + gch * 8;

  auto STAGE = [&](int buf, int j0) {
    gl16(kG + (size_t)j0 * 64, &Ks[buf][(w * 8) * 64]);
    gl16(vG + j0, &Vs[buf][(w * 8) * 64]);
  };

  bf16x8 qf[2];
  {
    const bf16* qp = qh + ((size_t)bh * kTok + (q0 + w * 16 + lr)) * 64 + lg * 8;
    qf[0] = *(const bf16x8*)qp;
    qf[1] = *(const bf16x8*)(qp + 32);
  }
  bf16x8 ones;
#pragma unroll
  for (int j = 0; j < 8; ++j) ones[j] = (bf16)1.0f;

  const f32x4 z = {0.f, 0.f, 0.f, 0.f};
  f32x4 o[4];
#pragma unroll
  for (int nf = 0; nf < 4; ++nf) o[nf] = z;
  f32x4 den = z;

  STAGE(0, 0);
#pragma unroll 1
  for (int jt = 0; jt < 9; ++jt) {              // 9 tiles = keys 0..575 exactly
    const int cur = jt & 1;
    __syncthreads();               // drains vmcnt(0): tile jt DMA done; prev reads done
    if (jt < 8) STAGE(cur ^ 1, (jt + 1) * 64);  // DMA overlaps compute below

    // S = Q K^T
    f32x4 s[4];
#pragma unroll
    for (int ni = 0; ni < 4; ++ni) s[ni] = z;
    __builtin_amdgcn_s_setprio(1);
#pragma unroll
    for (int kc = 0; kc < 2; ++kc) {
#pragma unroll
      for (int ni = 0; ni < 4; ++ni) {
        int row = ni * 16 + lr;
        bf16x8 kf = *(const bf16x8*)&Ks[cur][row * 64 + (((kc * 4 + lg) ^ (row & 7)) << 3)];
        s[ni] = __builtin_amdgcn_mfma_f32_16x16x32_bf16(qf[kc], kf, s[ni], 0, 0, 0);
      }
    }
    __builtin_amdgcn_s_setprio(0);

    // P = exp(S)  (no masking needed: all 64 keys of every tile are valid)
#pragma unroll
    for (int ni = 0; ni < 4; ++ni)
#pragma unroll
      for (int r = 0; r < 4; ++r) {
        float p = __expf(s[ni][r]);
        int prow = lg * 4 + r;
        int pcol = ni * 16 + lr;
        Ps[w][prow * 64 + ((((pcol >> 3) ^ (prow & 7)) & 7) << 3) + (pcol & 7)] = (bf16)p;
      }

    // O += P V ; den += P 1
    __builtin_amdgcn_s_setprio(1);
#pragma unroll
    for (int kc = 0; kc < 2; ++kc) {
      bf16x8 pf = *(const bf16x8*)&Ps[w][lr * 64 + (((kc * 4 + lg) ^ (lr & 7)) << 3)];
      den = __builtin_amdgcn_mfma_f32_16x16x32_bf16(pf, ones, den, 0, 0, 0);
#pragma unroll
      for (int nf = 0; nf < 4; ++nf) {
        int row = nf * 16 + lr;
        bf16x8 vf = *(const bf16x8*)&Vs[cur][row * 64 + (((kc * 4 + lg) ^ (row & 7)) << 3)];
        o[nf] = __builtin_amdgcn_mfma_f32_16x16x32_bf16(pf, vf, o[nf], 0, 0, 0);
      }
    }
    __builtin_amdgcn_s_setprio(0);
  }

  // key 576 (the 577th key) analytic correction: s = q . k576 per q-row
  {
    const bf16* k576 = kbq + ((size_t)bh * kTok + 576) * 64;
    bf16x8 ka = *(const bf16x8*)(k576 + lg * 8);
    bf16x8 kb2 = *(const bf16x8*)(k576 + 32 + lg * 8);
    float part = 0.f;
#pragma unroll
    for (int j = 0; j < 8; ++j)
      part += (float)qf[0][j] * (float)ka[j] + (float)qf[1][j] * (float)kb2[j];
    part += __shfl_xor(part, 16);
    part += __shfl_xor(part, 32);          // s for q-row (w*16 + lr), uniform over lg
    float v576[4];
#pragma unroll
    for (int nf = 0; nf < 4; ++nf)
      v576[nf] = (float)vtb[((size_t)bh * 64 + nf * 16 + lr) * kTok + 576];
#pragma unroll
    for (int r = 0; r < 4; ++r) {
      float p = __expf(__shfl(part, lg * 4 + r));   // row lg*4+r held by lane lr==lg*4+r
      den[r] += p;
#pragma unroll
      for (int nf = 0; nf < 4; ++nf) o[nf][r] += p * v576[nf];
    }
  }

  // epilogue: normalize by den, single bf16 output
  const int b = bh / 12, h = bh % 12;
#pragma unroll
  for (int r = 0; r < 4; ++r) {
    const int tok = q0 + w * 16 + lg * 4 + r;
    if (tok > 576) continue;
    const float inv = 1.0f / den[r];
    const size_t rowb = ((size_t)(b * kNtok + tok)) * kC + h * 64;
#pragma unroll
    for (int nf = 0; nf < 4; ++nf)
      aoh[rowb + nf * 16 + lr] = (bf16)(o[nf][r] * inv);
  }
}

// ---------------- proj GEMM: r7 template, single-A, BK=64, 8 waves --------------
__global__ __launch_bounds__(512, 4) void proj_gemm_kernel(
    const bf16* __restrict__ ah, const bf16* __restrict__ bw,
    const float* __restrict__ bias, float* __restrict__ out) {
  __shared__ __align__(16) char smem[65536];
  bf16* AsB = (bf16*)smem;
  bf16* BsB = (bf16*)(smem + 32768);
  const int tid = (int)threadIdx.x;
  const int l = tid & 63, w = tid >> 6;
  const int lr = l & 15, lg = l >> 4;
  const int wr = (w & 3) * 32, wc = (w >> 2) * 64;

  const int lid = swz_lid((int)blockIdx.x, 6 * 73);
  const int n0 = (lid % 6) * 128, m0 = (lid / 6) * 128;

  const int srow = w * 16 + (l >> 3);
  const int gch = (l & 7) ^ ((l >> 3) & 7);
  const bf16* aG = ah + (size_t)(m0 + srow) * kC + gch * 8;
  const bf16* bG = bw + (size_t)(n0 + srow) * kC + gch * 8;

  f32x4 acc[2][4];
  const f32x4 z = {0.f, 0.f, 0.f, 0.f};
#pragma unroll
  for (int mi = 0; mi < 2; ++mi)
#pragma unroll
    for (int ni = 0; ni < 4; ++ni) acc[mi][ni] = z;

  auto STAGE = [&](int buf, int k0) {
#pragma unroll
    for (int i = 0; i < 2; ++i) {
      gl16(aG + (size_t)i * 8 * kC + k0, &AsB[buf * 8192 + (w * 16 + i * 8) * 64]);
      gl16(bG + (size_t)i * 8 * kC + k0, &BsB[buf * 8192 + (w * 16 + i * 8) * 64]);
    }
  };
  auto COMPUTE = [&](int buf) {
    __builtin_amdgcn_s_setprio(1);
#pragma unroll
    for (int kc = 0; kc < 2; ++kc) {
      bf16x8 af[2], bfr[4];
#pragma unroll
      for (int ni = 0; ni < 4; ++ni) {
        int row = wc + ni * 16 + lr;
        bfr[ni] = *(const bf16x8*)&BsB[buf * 8192 + row * 64 + (((kc * 4 + lg) ^ (lr & 7)) << 3)];
      }
#pragma unroll
      for (int mi = 0; mi < 2; ++mi) {
        int row = wr + mi * 16 + lr;
        af[mi] = *(const bf16x8*)&AsB[buf * 8192 + row * 64 + (((kc * 4 + lg) ^ (lr & 7)) << 3)];
      }
#pragma unroll
      for (int mi = 0; mi < 2; ++mi)
#pragma unroll
        for (int ni = 0; ni < 4; ++ni)
          acc[mi][ni] = __builtin_amdgcn_mfma_f32_16x16x32_bf16(af[mi], bfr[ni], acc[mi][ni], 0, 0, 0);
    }
    __builtin_amdgcn_s_setprio(0);
  };

  STAGE(0, 0);
#pragma unroll 1
  for (int t = 0; t < 11; ++t) {
    const int buf = t & 1;
    STAGE(buf ^ 1, (t + 1) * 64);
    asm volatile("s_waitcnt vmcnt(4)" ::: "memory");
    __builtin_amdgcn_sched_barrier(0);
    __builtin_amdgcn_s_barrier();
    COMPUTE(buf);
    __builtin_amdgcn_s_barrier();
    __builtin_amdgcn_sched_barrier(0);
  }
  asm volatile("s_waitcnt vmcnt(0)" ::: "memory");
  __builtin_amdgcn_sched_barrier(0);
  __builtin_amdgcn_s_barrier();
  COMPUTE(1);

  __syncthreads();
  float* tp = (float*)smem + w * 2048;
#pragma unroll
  for (int mi = 0; mi < 2; ++mi)
#pragma unroll
    for (int ni = 0; ni < 4; ++ni)
#pragma unroll
      for (int r = 0; r < 4; ++r)
        tp[(mi * 16 + lg * 4 + r) * 64 + ni * 16 + lr] = acc[mi][ni][r];

  const int c4 = lr * 4;
  const int ncol = n0 + wc + c4;
  float4 bv = *(const float4*)&bias[ncol];
#pragma unroll
  for (int i = 0; i < 8; ++i) {
    const int row = i * 4 + lg;
    const int m = m0 + wr + row;
    if (m >= kM) continue;
    float4 v4 = *(const float4*)&tp[row * 64 + c4];
    v4.x += bv.x; v4.y += bv.y; v4.z += bv.z; v4.w += bv.w;
    *(float4*)(out + (size_t)m * kC + ncol) = v4;
  }
}

// ---------------- launch ----------------
extern "C" void kernel_launch(void* const* d_in, const int* in_sizes, int n_in,
                              void* d_out, int out_size, void* d_ws, size_t ws_size,
                              hipStream_t stream) {
  const float* x = (const float*)d_in[0];
  const float* qkv_w = (const float*)d_in[1];
  const float* proj_w = (const float*)d_in[2];
  const float* proj_b = (const float*)d_in[3];
  const float* freqs = (const float*)d_in[4];
  float* out = (float*)d_out;

  char* p = (char*)d_ws;
  auto take = [&](size_t bytes) { char* r = p; p += (bytes + 255) & ~(size_t)255; return r; };
  float* cosT = (float*)take(221184 * 4);
  float* sinT = (float*)take(221184 * 4);
  bf16* xb   = (bf16*)take((size_t)kMpad * kC * 2);
  bf16* wqb  = (bf16*)take((size_t)2304 * kC * 2);
  bf16* pwb  = (bf16*)take((size_t)kC * kC * 2);
  bf16* qh   = (bf16*)take((size_t)kBH * kTok * 64 * 2);
  bf16* kbq  = (bf16*)take((size_t)kBH * kTok * 64 * 2);
  bf16* vtb  = (bf16*)take((size_t)kBH * 64 * kTok * 2);
  bf16* aoh  = (bf16*)take((size_t)kMpad * kC * 2);

  prep_kernel<<<3504 + 864 + 288 + 864, 256, 0, stream>>>(
      x, qkv_w, proj_w, freqs, xb, wqb, pwb, cosT, sinT);
  qkv_gemm_kernel<<<dim3(18 * 73), 512, 0, stream>>>(xb, wqb, cosT, sinT, qh, kbq, vtb);
  attn_kernel<<<dim3(5 * kBH), 512, 0, stream>>>(qh, kbq, vtb, aoh);
  proj_gemm_kernel<<<dim3(6 * 73), 512, 0, stream>>>(aoh, pwb, proj_b, out);
}

// Round 6
// 110.317 us; speedup vs baseline: 1.2083x; 1.0071x over previous
//
#include <hip/hip_runtime.h>

// RoPEAttention MI355X round 19:
//  qkv : r7 2-phase schedule kept EXACTLY; tile 192x128 (was 128x128).
//        Grid 882=49x18 -> max 4 blk/CU x 1.5W == old 6W quantization, so the
//        delta is pure per-block efficiency: 24 MFMA / 14 ds_read / 5 gl16 per
//        K-step (vs 16/12/4). LDS 80KB (A 2x24KB + B 2x16KB) -> 2 blk/CU (same).
//        Epilogue: 3 chunks of 16 rows in 10KB/wave region (f32 RoPE path,
//        bf16 stride-65 V-transpose path).
//  attn/proj/prep: unchanged from round 18 (111.1us proven).

typedef __bf16 bf16;
typedef __bf16 bf16x4 __attribute__((ext_vector_type(4)));
typedef __bf16 bf16x8 __attribute__((ext_vector_type(8)));
typedef float f32x4 __attribute__((ext_vector_type(4)));

namespace {
constexpr int kC = 768;
constexpr int kNtok = 577;
constexpr int kM = 16 * kNtok;     // 9232
constexpr int kMpadQ = 9408;       // 49 * 192 (qkv A pad)
constexpr int kMpadP = 9344;       // 73 * 128 (proj A pad)
constexpr int kTok = 640;
constexpr int kBH = 192;
}

typedef __attribute__((address_space(3))) unsigned int as3_u32;
typedef __attribute__((address_space(1))) unsigned int as1_u32;
__device__ __forceinline__ void gl16(const bf16* g, bf16* l) {
  __builtin_amdgcn_global_load_lds((const as1_u32*)g, (as3_u32*)l, 16, 0, 0);
}

// m204 bijective XCD swizzle
__device__ __forceinline__ int swz_lid(int hid, int nwg) {
  int q = nwg >> 3, r = nwg & 7;
  int x = hid & 7, y = hid >> 3;
  int base = (x < r) ? x * (q + 1) : r * (q + 1) + (x - r) * q;
  return base + y;
}

// ---------------- fused prep: conv_x | conv_w(qkv) | conv_w(proj) | rope --------
__global__ __launch_bounds__(256) void prep_kernel(
    const float* __restrict__ x, const float* __restrict__ qkv_w,
    const float* __restrict__ proj_w, const float* __restrict__ freqs,
    bf16* __restrict__ xb, bf16* __restrict__ wqb, bf16* __restrict__ pwb,
    float* __restrict__ cosT, float* __restrict__ sinT) {
  const int bidx = (int)blockIdx.x;
  const int tid = (int)threadIdx.x;
  if (bidx < 3528) {                       // conv_x: kMpadQ*96 chunks of 8
    int idx = bidx * 256 + tid;
    int m = idx / 96, c8 = (idx % 96) * 8;
    bf16x8 o;
    if (m < kM) {
      const float* p = x + (size_t)m * kC + c8;
#pragma unroll
      for (int j = 0; j < 8; ++j) o[j] = (bf16)p[j];
    } else {
#pragma unroll
      for (int j = 0; j < 8; ++j) o[j] = (bf16)0.0f;
    }
    *(bf16x8*)(xb + (size_t)m * kC + c8) = o;
  } else if (bidx < 3528 + 864) {          // conv_w qkv: 2304*768
    int off = ((bidx - 3528) * 256 + tid) * 8;
    bf16x8 o;
#pragma unroll
    for (int j = 0; j < 8; ++j) o[j] = (bf16)qkv_w[off + j];
    *(bf16x8*)(wqb + off) = o;
  } else if (bidx < 3528 + 864 + 288) {    // conv_w proj: 768*768
    int off = ((bidx - 3528 - 864) * 256 + tid) * 8;
    bf16x8 o;
#pragma unroll
    for (int j = 0; j < 8; ++j) o[j] = (bf16)proj_w[off + j];
    *(bf16x8*)(pwb + off) = o;
  } else {                                 // rope table: 12*576*32
    int idx = (bidx - 3528 - 864 - 288) * 256 + tid;
    int f = idx & 31;
    int t = (idx >> 5) % 576;
    int h = idx / (576 * 32);
    float ang = (float)(t % 24) * freqs[h * 32 + f] + (float)(t / 24) * freqs[384 + h * 32 + f];
    float s, c;
    sincosf(ang, &s, &c);
    cosT[idx] = c;
    sinT[idx] = s;
  }
}

// ---------------- qkv GEMM 192x128, 8 waves (4M x 2N, wave 48x64), BK=64 --------
// r7 2-phase counted-vmcnt schedule; 5 gl16/thread per STAGE -> vmcnt(5).
__global__ __launch_bounds__(512, 4) void qkv_gemm_kernel(
    const bf16* __restrict__ xb, const bf16* __restrict__ wb,
    const float* __restrict__ cosT, const float* __restrict__ sinT,
    bf16* __restrict__ qh, bf16* __restrict__ kbq, bf16* __restrict__ vtb) {
  __shared__ __align__(16) char smem[81920];
  bf16* AsB = (bf16*)smem;             // [2][192*64] = 48 KB
  bf16* BsB = (bf16*)(smem + 49152);   // [2][128*64] = 32 KB
  const int tid = (int)threadIdx.x;
  const int l = tid & 63, w = tid >> 6;        // 8 waves
  const int lr = l & 15, lg = l >> 4;
  const int wr = (w & 3) * 48, wc = (w >> 2) * 64;   // wave tile 48x64

  const int lid = swz_lid((int)blockIdx.x, 49 * 18);
  const int n0 = (lid % 18) * 128, m0 = (lid / 18) * 192;

  const int srow = w * 8 + (l >> 3);           // 64 rows per staging pass
  const int gch = (l & 7) ^ ((l >> 3) & 7);    // pre-swizzled global chunk
  const bf16* aG = xb + (size_t)(m0 + srow) * kC + gch * 8;
  const bf16* bG = wb + (size_t)(n0 + srow) * kC + gch * 8;

  f32x4 acc[3][4];
  const f32x4 z = {0.f, 0.f, 0.f, 0.f};
#pragma unroll
  for (int mi = 0; mi < 3; ++mi)
#pragma unroll
    for (int ni = 0; ni < 4; ++ni) acc[mi][ni] = z;

  auto STAGE = [&](int buf, int k0) {
#pragma unroll
    for (int i = 0; i < 3; ++i)
      gl16(aG + (size_t)i * 64 * kC + k0, &AsB[buf * 12288 + (i * 64 + w * 8) * 64]);
#pragma unroll
    for (int j = 0; j < 2; ++j)
      gl16(bG + (size_t)j * 64 * kC + k0, &BsB[buf * 8192 + (j * 64 + w * 8) * 64]);
  };
  auto COMPUTE = [&](int buf) {
    __builtin_amdgcn_s_setprio(1);
#pragma unroll
    for (int kc = 0; kc < 2; ++kc) {
      bf16x8 af[3], bfr[4];
#pragma unroll
      for (int ni = 0; ni < 4; ++ni) {
        int row = wc + ni * 16 + lr;
        bfr[ni] = *(const bf16x8*)&BsB[buf * 8192 + row * 64 + (((kc * 4 + lg) ^ (lr & 7)) << 3)];
      }
#pragma unroll
      for (int mi = 0; mi < 3; ++mi) {
        int row = wr + mi * 16 + lr;
        af[mi] = *(const bf16x8*)&AsB[buf * 12288 + row * 64 + (((kc * 4 + lg) ^ (lr & 7)) << 3)];
      }
#pragma unroll
      for (int mi = 0; mi < 3; ++mi)
#pragma unroll
        for (int ni = 0; ni < 4; ++ni)
          acc[mi][ni] = __builtin_amdgcn_mfma_f32_16x16x32_bf16(af[mi], bfr[ni], acc[mi][ni], 0, 0, 0);
    }
    __builtin_amdgcn_s_setprio(0);
  };

  STAGE(0, 0);
#pragma unroll 1
  for (int t = 0; t < 11; ++t) {
    const int buf = t & 1;
    STAGE(buf ^ 1, (t + 1) * 64);
    asm volatile("s_waitcnt vmcnt(5)" ::: "memory");
    __builtin_amdgcn_sched_barrier(0);
    __builtin_amdgcn_s_barrier();
    COMPUTE(buf);
    __builtin_amdgcn_s_barrier();
    __builtin_amdgcn_sched_barrier(0);
  }
  asm volatile("s_waitcnt vmcnt(0)" ::: "memory");
  __builtin_amdgcn_sched_barrier(0);
  __builtin_amdgcn_s_barrier();
  COMPUTE(1);

  // ---- epilogue: 3 chunks of 16 rows per wave (10 KB wave-private region) ----
  __syncthreads();
  const int which = n0 / kC;
  const int h = ((n0 + wc) % kC) >> 6;             // wave-uniform head (wc in {0,64})

  if (which == 2) {
    // Fused V transpose per chunk: bf16 tile [16][stride 65] (no aliasing,
    // <=2-way banks), stores: lanes = 16 toks x 4 d-phases, d = it*4 + (l>>4).
    bf16* tq = (bf16*)smem + w * 5120;             // 10 KB region, uses 2080 B
    const int tokrow = lr;
    const int dl = lg;
#pragma unroll
    for (int mi = 0; mi < 3; ++mi) {
#pragma unroll
      for (int ni = 0; ni < 4; ++ni)
#pragma unroll
        for (int r = 0; r < 4; ++r)
          tq[(lg * 4 + r) * 65 + ni * 16 + lr] = (bf16)acc[mi][ni][r];
      __builtin_amdgcn_sched_barrier(0);           // keep write->read->overwrite order
      const int m = m0 + wr + mi * 16 + tokrow;
      if (m < kM) {
        const int b = m / kNtok;
        const int tok = m - b * kNtok;
        bf16* vdst = vtb + ((size_t)(b * 12 + h) * 64 + dl) * kTok + tok;
#pragma unroll
        for (int it = 0; it < 16; ++it)
          vdst[(size_t)(it * 4) * kTok] = tq[tokrow * 65 + it * 4 + dl];
      }
      __builtin_amdgcn_sched_barrier(0);
    }
  } else {
    // Q/K: per chunk restage f32 [16][64], vectorized RoPE + coalesced stores
    float* tp = (float*)smem + w * 2560;           // 10 KB region, uses 4 KB
    bf16* dst = (which == 0) ? qh : kbq;
    const float sc = (which == 0) ? 0.125f : 1.0f;
    const int c4 = lr * 4;
#pragma unroll
    for (int mi = 0; mi < 3; ++mi) {
#pragma unroll
      for (int ni = 0; ni < 4; ++ni)
#pragma unroll
        for (int r = 0; r < 4; ++r)
          tp[(lg * 4 + r) * 64 + ni * 16 + lr] = acc[mi][ni][r];
      __builtin_amdgcn_sched_barrier(0);
#pragma unroll
      for (int i = 0; i < 4; ++i) {
        const int row = i * 4 + lg;
        const int m = m0 + wr + mi * 16 + row;
        if (m >= kM) continue;
        float4 v4 = *(const float4*)&tp[row * 64 + c4];
        const int b = m / kNtok;
        const int tok = m - b * kNtok;
        float e0 = v4.x, o0 = v4.y, e1 = v4.z, o1 = v4.w;
        if (tok > 0) {
          const int tb = (h * 576 + tok - 1) * 32 + (c4 >> 1);
          float2 cc = *(const float2*)&cosT[tb];
          float2 ss = *(const float2*)&sinT[tb];
          float r0 = e0 * cc.x - o0 * ss.x, i0 = e0 * ss.x + o0 * cc.x;
          float r1 = e1 * cc.y - o1 * ss.y, i1 = e1 * ss.y + o1 * cc.y;
          e0 = r0; o0 = i0; e1 = r1; o1 = i1;
        }
        bf16x4 ov;
        ov[0] = (bf16)(e0 * sc); ov[1] = (bf16)(o0 * sc);
        ov[2] = (bf16)(e1 * sc); ov[3] = (bf16)(o1 * sc);
        *(bf16x4*)(dst + (((size_t)(b * 12 + h)) * kTok + tok) * 64 + c4) = ov;
      }
      __builtin_amdgcn_sched_barrier(0);
    }
  }
}

// ---------------- flash attention: 8 waves, 9 exact K-tiles + key-576 -----------
__global__ __launch_bounds__(512, 8) void attn_kernel(
    const bf16* __restrict__ qh, const bf16* __restrict__ kbq, const bf16* __restrict__ vtb,
    bf16* __restrict__ aoh) {
  __shared__ __align__(16) bf16 Ks[2][64 * 64];   // 16 KB
  __shared__ __align__(16) bf16 Vs[2][64 * 64];   // 16 KB
  __shared__ __align__(16) bf16 Ps[8][16 * 64];   // 16 KB
  const int tid = (int)threadIdx.x;
  const int l = tid & 63, w = tid >> 6;           // 8 waves
  const int lr = l & 15, lg = l >> 4;

  const int lid = swz_lid((int)blockIdx.x, 5 * kBH);
  const int bh = lid / 5, qt = lid - bh * 5;      // all 5 q-tiles of a bh -> one XCD
  const int q0 = qt * 128;

  const int srow = w * 8 + (l >> 3);
  const int gch = (l & 7) ^ ((l >> 3) & 7);
  const bf16* kG = kbq + ((size_t)bh * kTok + srow) * 64 + gch * 8;
  const bf16* vG = vtb + ((size_t)bh * 64 + srow) * kTok + gch * 8;

  auto STAGE = [&](int buf, int j0) {
    gl16(kG + (size_t)j0 * 64, &Ks[buf][(w * 8) * 64]);
    gl16(vG + j0, &Vs[buf][(w * 8) * 64]);
  };

  bf16x8 qf[2];
  {
    const bf16* qp = qh + ((size_t)bh * kTok + (q0 + w * 16 + lr)) * 64 + lg * 8;
    qf[0] = *(const bf16x8*)qp;
    qf[1] = *(const bf16x8*)(qp + 32);
  }
  bf16x8 ones;
#pragma unroll
  for (int j = 0; j < 8; ++j) ones[j] = (bf16)1.0f;

  const f32x4 z = {0.f, 0.f, 0.f, 0.f};
  f32x4 o[4];
#pragma unroll
  for (int nf = 0; nf < 4; ++nf) o[nf] = z;
  f32x4 den = z;

  STAGE(0, 0);
#pragma unroll 1
  for (int jt = 0; jt < 9; ++jt) {              // 9 tiles = keys 0..575 exactly
    const int cur = jt & 1;
    __syncthreads();               // drains vmcnt(0): tile jt DMA done; prev reads done
    if (jt < 8) STAGE(cur ^ 1, (jt + 1) * 64);  // DMA overlaps compute below

    // S = Q K^T
    f32x4 s[4];
#pragma unroll
    for (int ni = 0; ni < 4; ++ni) s[ni] = z;
    __builtin_amdgcn_s_setprio(1);
#pragma unroll
    for (int kc = 0; kc < 2; ++kc) {
#pragma unroll
      for (int ni = 0; ni < 4; ++ni) {
        int row = ni * 16 + lr;
        bf16x8 kf = *(const bf16x8*)&Ks[cur][row * 64 + (((kc * 4 + lg) ^ (row & 7)) << 3)];
        s[ni] = __builtin_amdgcn_mfma_f32_16x16x32_bf16(qf[kc], kf, s[ni], 0, 0, 0);
      }
    }
    __builtin_amdgcn_s_setprio(0);

    // P = exp(S)  (no masking needed: all 64 keys of every tile are valid)
#pragma unroll
    for (int ni = 0; ni < 4; ++ni)
#pragma unroll
      for (int r = 0; r < 4; ++r) {
        float p = __expf(s[ni][r]);
        int prow = lg * 4 + r;
        int pcol = ni * 16 + lr;
        Ps[w][prow * 64 + ((((pcol >> 3) ^ (prow & 7)) & 7) << 3) + (pcol & 7)] = (bf16)p;
      }

    // O += P V ; den += P 1
    __builtin_amdgcn_s_setprio(1);
#pragma unroll
    for (int kc = 0; kc < 2; ++kc) {
      bf16x8 pf = *(const bf16x8*)&Ps[w][lr * 64 + (((kc * 4 + lg) ^ (lr & 7)) << 3)];
      den = __builtin_amdgcn_mfma_f32_16x16x32_bf16(pf, ones, den, 0, 0, 0);
#pragma unroll
      for (int nf = 0; nf < 4; ++nf) {
        int row = nf * 16 + lr;
        bf16x8 vf = *(const bf16x8*)&Vs[cur][row * 64 + (((kc * 4 + lg) ^ (row & 7)) << 3)];
        o[nf] = __builtin_amdgcn_mfma_f32_16x16x32_bf16(pf, vf, o[nf], 0, 0, 0);
      }
    }
    __builtin_amdgcn_s_setprio(0);
  }

  // key 576 (the 577th key) analytic correction: s = q . k576 per q-row
  {
    const bf16* k576 = kbq + ((size_t)bh * kTok + 576) * 64;
    bf16x8 ka = *(const bf16x8*)(k576 + lg * 8);
    bf16x8 kb2 = *(const bf16x8*)(k576 + 32 + lg * 8);
    float part = 0.f;
#pragma unroll
    for (int j = 0; j < 8; ++j)
      part += (float)qf[0][j] * (float)ka[j] + (float)qf[1][j] * (float)kb2[j];
    part += __shfl_xor(part, 16);
    part += __shfl_xor(part, 32);          // s for q-row (w*16 + lr), uniform over lg
    float v576[4];
#pragma unroll
    for (int nf = 0; nf < 4; ++nf)
      v576[nf] = (float)vtb[((size_t)bh * 64 + nf * 16 + lr) * kTok + 576];
#pragma unroll
    for (int r = 0; r < 4; ++r) {
      float p = __expf(__shfl(part, lg * 4 + r));   // row lg*4+r held by lane lr==lg*4+r
      den[r] += p;
#pragma unroll
      for (int nf = 0; nf < 4; ++nf) o[nf][r] += p * v576[nf];
    }
  }

  // epilogue: normalize by den, single bf16 output
  const int b = bh / 12, h = bh % 12;
#pragma unroll
  for (int r = 0; r < 4; ++r) {
    const int tok = q0 + w * 16 + lg * 4 + r;
    if (tok > 576) continue;
    const float inv = 1.0f / den[r];
    const size_t rowb = ((size_t)(b * kNtok + tok)) * kC + h * 64;
#pragma unroll
    for (int nf = 0; nf < 4; ++nf)
      aoh[rowb + nf * 16 + lr] = (bf16)(o[nf][r] * inv);
  }
}

// ---------------- proj GEMM: r7 template, single-A, BK=64, 8 waves --------------
__global__ __launch_bounds__(512, 4) void proj_gemm_kernel(
    const bf16* __restrict__ ah, const bf16* __restrict__ bw,
    const float* __restrict__ bias, float* __restrict__ out) {
  __shared__ __align__(16) char smem[65536];
  bf16* AsB = (bf16*)smem;
  bf16* BsB = (bf16*)(smem + 32768);
  const int tid = (int)threadIdx.x;
  const int l = tid & 63, w = tid >> 6;
  const int lr = l & 15, lg = l >> 4;
  const int wr = (w & 3) * 32, wc = (w >> 2) * 64;

  const int lid = swz_lid((int)blockIdx.x, 6 * 73);
  const int n0 = (lid % 6) * 128, m0 = (lid / 6) * 128;

  const int srow = w * 16 + (l >> 3);
  const int gch = (l & 7) ^ ((l >> 3) & 7);
  const bf16* aG = ah + (size_t)(m0 + srow) * kC + gch * 8;
  const bf16* bG = bw + (size_t)(n0 + srow) * kC + gch * 8;

  f32x4 acc[2][4];
  const f32x4 z = {0.f, 0.f, 0.f, 0.f};
#pragma unroll
  for (int mi = 0; mi < 2; ++mi)
#pragma unroll
    for (int ni = 0; ni < 4; ++ni) acc[mi][ni] = z;

  auto STAGE = [&](int buf, int k0) {
#pragma unroll
    for (int i = 0; i < 2; ++i) {
      gl16(aG + (size_t)i * 8 * kC + k0, &AsB[buf * 8192 + (w * 16 + i * 8) * 64]);
      gl16(bG + (size_t)i * 8 * kC + k0, &BsB[buf * 8192 + (w * 16 + i * 8) * 64]);
    }
  };
  auto COMPUTE = [&](int buf) {
    __builtin_amdgcn_s_setprio(1);
#pragma unroll
    for (int kc = 0; kc < 2; ++kc) {
      bf16x8 af[2], bfr[4];
#pragma unroll
      for (int ni = 0; ni < 4; ++ni) {
        int row = wc + ni * 16 + lr;
        bfr[ni] = *(const bf16x8*)&BsB[buf * 8192 + row * 64 + (((kc * 4 + lg) ^ (lr & 7)) << 3)];
      }
#pragma unroll
      for (int mi = 0; mi < 2; ++mi) {
        int row = wr + mi * 16 + lr;
        af[mi] = *(const bf16x8*)&AsB[buf * 8192 + row * 64 + (((kc * 4 + lg) ^ (lr & 7)) << 3)];
      }
#pragma unroll
      for (int mi = 0; mi < 2; ++mi)
#pragma unroll
        for (int ni = 0; ni < 4; ++ni)
          acc[mi][ni] = __builtin_amdgcn_mfma_f32_16x16x32_bf16(af[mi], bfr[ni], acc[mi][ni], 0, 0, 0);
    }
    __builtin_amdgcn_s_setprio(0);
  };

  STAGE(0, 0);
#pragma unroll 1
  for (int t = 0; t < 11; ++t) {
    const int buf = t & 1;
    STAGE(buf ^ 1, (t + 1) * 64);
    asm volatile("s_waitcnt vmcnt(4)" ::: "memory");
    __builtin_amdgcn_sched_barrier(0);
    __builtin_amdgcn_s_barrier();
    COMPUTE(buf);
    __builtin_amdgcn_s_barrier();
    __builtin_amdgcn_sched_barrier(0);
  }
  asm volatile("s_waitcnt vmcnt(0)" ::: "memory");
  __builtin_amdgcn_sched_barrier(0);
  __builtin_amdgcn_s_barrier();
  COMPUTE(1);

  __syncthreads();
  float* tp = (float*)smem + w * 2048;
#pragma unroll
  for (int mi = 0; mi < 2; ++mi)
#pragma unroll
    for (int ni = 0; ni < 4; ++ni)
#pragma unroll
      for (int r = 0; r < 4; ++r)
        tp[(mi * 16 + lg * 4 + r) * 64 + ni * 16 + lr] = acc[mi][ni][r];

  const int c4 = lr * 4;
  const int ncol = n0 + wc + c4;
  float4 bv = *(const float4*)&bias[ncol];
#pragma unroll
  for (int i = 0; i < 8; ++i) {
    const int row = i * 4 + lg;
    const int m = m0 + wr + row;
    if (m >= kM) continue;
    float4 v4 = *(const float4*)&tp[row * 64 + c4];
    v4.x += bv.x; v4.y += bv.y; v4.z += bv.z; v4.w += bv.w;
    *(float4*)(out + (size_t)m * kC + ncol) = v4;
  }
}

// ---------------- launch ----------------
extern "C" void kernel_launch(void* const* d_in, const int* in_sizes, int n_in,
                              void* d_out, int out_size, void* d_ws, size_t ws_size,
                              hipStream_t stream) {
  const float* x = (const float*)d_in[0];
  const float* qkv_w = (const float*)d_in[1];
  const float* proj_w = (const float*)d_in[2];
  const float* proj_b = (const float*)d_in[3];
  const float* freqs = (const float*)d_in[4];
  float* out = (float*)d_out;

  char* p = (char*)d_ws;
  auto take = [&](size_t bytes) { char* r = p; p += (bytes + 255) & ~(size_t)255; return r; };
  float* cosT = (float*)take(221184 * 4);
  float* sinT = (float*)take(221184 * 4);
  bf16* xb   = (bf16*)take((size_t)kMpadQ * kC * 2);
  bf16* wqb  = (bf16*)take((size_t)2304 * kC * 2);
  bf16* pwb  = (bf16*)take((size_t)kC * kC * 2);
  bf16* qh   = (bf16*)take((size_t)kBH * kTok * 64 * 2);
  bf16* kbq  = (bf16*)take((size_t)kBH * kTok * 64 * 2);
  bf16* vtb  = (bf16*)take((size_t)kBH * 64 * kTok * 2);
  bf16* aoh  = (bf16*)take((size_t)kMpadP * kC * 2);

  prep_kernel<<<3528 + 864 + 288 + 864, 256, 0, stream>>>(
      x, qkv_w, proj_w, freqs, xb, wqb, pwb, cosT, sinT);
  qkv_gemm_kernel<<<dim3(49 * 18), 512, 0, stream>>>(xb, wqb, cosT, sinT, qh, kbq, vtb);
  attn_kernel<<<dim3(5 * kBH), 512, 0, stream>>>(qh, kbq, vtb, aoh);
  proj_gemm_kernel<<<dim3(6 * 73), 512, 0, stream>>>(aoh, pwb, proj_b, out);
}